// Round 1
// baseline (709.017 us; speedup 1.0000x reference)
//
#include <hip/hip_runtime.h>
#include <hip/hip_bf16.h>

// S2Attention, dtype-adaptive, MFMA pipeline.
// B=8 C=512 H=W=64 HEADS=8 d=64 R=4 -> k/v spatial 17x17=289 (padded 320).
//
//  0) detect:  flag = externals f32 (1) vs bf16 (0)
//  0b) cvt_w:  wq, wout -> bf16 [512*512] (sanitized)
//  1) transpose_cvt: sem [z][512][4096] -> semT [z][4096][512] bf16
//  2) dwconv:  spa,x -> tk,tv [B,C,289] f32 (plane-tiled, coalesced)
//  3) lnorm_c: channel LayerNorm, in-place f32
//  4) kv gemm (scalar): k -> ktr bf16 [64][289][64]; v -> vtr bf16 [64][64][320]
//     (+ zpad_v zeroes vtr cols 289..319)
//  5) gemm_mfma epi=1: q = wq @ sem -> qt bf16 [64][4096][64] in d_out (x0.125 folded)
//  6) attn_mfma: flash-style, no-rescale softmax, K/V from global -> attT bf16
//  7) gemm_mfma epi=0: out = wout @ att -> d_out (flag dtype)

#define BATCH 8
#define CH 512
#define HW 4096
#define NHEADS 8
#define HD 64
#define PP 289
#define NKP 320

typedef __attribute__((ext_vector_type(8))) short bf16x8;
typedef __attribute__((ext_vector_type(4))) float f32x4;

__device__ inline float sanitize(float x) {
    unsigned u = __float_as_uint(x);
    if ((u & 0x7F800000u) == 0x7F800000u) return 0.0f;
    return x;
}
__device__ inline float ldin(const void* p, size_t i, int f32) {
    float x = f32 ? ((const float*)p)[i]
                  : __bfloat162float(((const __hip_bfloat16*)p)[i]);
    return sanitize(x);
}
__device__ inline void stout(void* p, size_t i, float v, int f32) {
    if (f32) ((float*)p)[i] = v;
    else     ((__hip_bfloat16*)p)[i] = __float2bfloat16(v);
}
__device__ inline short f2bf(float x) {   // RNE f32->bf16 (inputs pre-sanitized)
    unsigned u = __float_as_uint(x);
    unsigned r = (u + 0x7FFFu + ((u >> 16) & 1u)) >> 16;
    return (short)r;
}
__device__ inline void gload_lds16(const void* g, void* l) {
    __builtin_amdgcn_global_load_lds(
        (const __attribute__((address_space(1))) void*)g,
        (__attribute__((address_space(3))) void*)l, 16, 0, 0);
}

// ---------------- dtype detector ----------------
__global__ void detect_dtype(const unsigned short* __restrict__ w, int* __restrict__ flag) {
    __shared__ int red[256];
    int tid = threadIdx.x;
    int cnt = 0;
    for (int i = tid; i < 8192; i += 256) {
        unsigned e = w[i] & 0x7F80u;
        cnt += (e >= 0x4300u) ? 1 : 0;
    }
    red[tid] = cnt;
    __syncthreads();
    for (int o = 128; o; o >>= 1) { if (tid < o) red[tid] += red[tid + o]; __syncthreads(); }
    if (tid == 0) *flag = (red[0] > 500) ? 1 : 0;
}

// ---------------- weight convert: [512*512] ext dtype -> bf16 ----------------
__global__ __launch_bounds__(256)
void cvt_w(const void* __restrict__ in, short* __restrict__ out, const int* __restrict__ flag) {
    const int f32 = *flag;
    int i = (blockIdx.x * 256 + threadIdx.x) * 8;
#pragma unroll
    for (int e = 0; e < 8; ++e) out[i + e] = f2bf(ldin(in, i + e, f32));
}

// ---------------- sem transpose+cvt: [z][512][4096] ext -> [z][4096][512] bf16 ----
__global__ __launch_bounds__(256)
void transpose_cvt(const void* __restrict__ in, short* __restrict__ outT,
                   const int* __restrict__ flag) {
    __shared__ short T[64 * 72];
    const int f32 = *flag;
    const int tid = threadIdx.x;
    const int z = blockIdx.z;
    const int c0 = blockIdx.y * 64, p0 = blockIdx.x * 64;
    {
        int c = tid >> 2, ps = (tid & 3) * 16;
        size_t src = ((size_t)z * CH + c0 + c) * HW + p0 + ps;
#pragma unroll
        for (int e = 0; e < 16; ++e)
            T[c * 72 + ps + e] = f2bf(ldin(in, src + e, f32));
    }
    __syncthreads();
    {
        int p = tid >> 2, cs = (tid & 3) * 16;
        union { short s[16]; int4 v[2]; } u;
#pragma unroll
        for (int e = 0; e < 16; ++e) u.s[e] = T[(cs + e) * 72 + p];
        short* op = outT + ((size_t)z * HW + p0 + p) * CH + c0 + cs;
        *(int4*)op = u.v[0];
        *(int4*)(op + 8) = u.v[1];
    }
}

// ---------------- depthwise 4x4 stride4 pad2 conv, plane-tiled ----------------
// one block per (b,c) plane: coalesced stage of 64x64 input into LDS, 289 outs.
__global__ __launch_bounds__(256)
void dwconv(const void* __restrict__ in, const void* __restrict__ w,
            float* __restrict__ out, const int* __restrict__ flag) {
    __shared__ float T[4096];
    __shared__ float wf[16];
    const int f32 = *flag;
    const int tid = threadIdx.x;
    const int bc = blockIdx.x;                 // b*CH + c
    const int c = bc & (CH - 1);
    size_t ibase = (size_t)bc * HW;
    if (tid < 16) wf[tid] = ldin(w, (size_t)c * 16 + tid, f32);
#pragma unroll
    for (int k = 0; k < 16; ++k)
        T[tid + k * 256] = ldin(in, ibase + tid + k * 256, f32);
    __syncthreads();
    for (int o = tid; o < PP; o += 256) {
        int oy = o / 17, ox = o % 17;
        float s = 0.f;
#pragma unroll
        for (int ky = 0; ky < 4; ++ky) {
            int iy = oy * 4 - 2 + ky;
            if ((unsigned)iy >= 64u) continue;
#pragma unroll
            for (int kx = 0; kx < 4; ++kx) {
                int ix = ox * 4 - 2 + kx;
                if ((unsigned)ix >= 64u) continue;
                s += T[iy * 64 + ix] * wf[ky * 4 + kx];
            }
        }
        out[(size_t)bc * PP + o] = s;
    }
}

// ---------------- channel LayerNorm (over C=512) ----------------
__global__ __launch_bounds__(256)
void lnorm_c(float* __restrict__ t, const void* __restrict__ g,
             const void* __restrict__ bb, const int* __restrict__ flag) {
    __shared__ float red[256];
    const int f32 = *flag;
    int tid = threadIdx.x;
    int pos = blockIdx.x % PP;
    int b = blockIdx.x / PP;
    float* base = t + (size_t)b * CH * PP + pos;
    int c0 = tid, c1 = tid + 256;
    float v0 = base[(size_t)c0 * PP];
    float v1 = base[(size_t)c1 * PP];
    red[tid] = v0 + v1;
    __syncthreads();
    for (int off = 128; off > 0; off >>= 1) {
        if (tid < off) red[tid] += red[tid + off];
        __syncthreads();
    }
    float mean = red[0] * (1.0f / 512.0f);
    __syncthreads();
    float d0 = v0 - mean, d1 = v1 - mean;
    red[tid] = d0 * d0 + d1 * d1;
    __syncthreads();
    for (int off = 128; off > 0; off >>= 1) {
        if (tid < off) red[tid] += red[tid + off];
        __syncthreads();
    }
    float var = red[0] * (1.0f / 512.0f);
    float rstd = rsqrtf(var + 1e-5f);
    base[(size_t)c0 * PP] = d0 * rstd * ldin(g, c0, f32) + ldin(bb, c0, f32);
    base[(size_t)c1 * PP] = d1 * rstd * ldin(g, c1, f32) + ldin(bb, c1, f32);
}

// ---------------- kv pointwise GEMM (scalar), N=289 ----------------
// c_mode 1: K bf16 [bh][289][64]; c_mode 2: V bf16 [bh][64][320]
__global__ __launch_bounds__(256)
void kv_gemm(const void* __restrict__ A, const float* __restrict__ Bm,
             short* __restrict__ Cm, const int* __restrict__ flag, int c_mode) {
    __shared__ float As[64][17];
    __shared__ float Bs[16][64];
    const int f32 = *flag;
    const int tid = threadIdx.x;
    const int tx = tid & 15, ty = tid >> 4;
    const int n0 = blockIdx.x * 64;
    const int m0 = blockIdx.y * 64;
    const size_t zoff = (size_t)blockIdx.z * CH * PP;

    float acc[4][4] = {};
    for (int k0 = 0; k0 < CH; k0 += 16) {
        {
            int m = tid >> 2;
            int kk = (tid & 3) * 4;
            size_t ab = (size_t)(m0 + m) * CH + k0 + kk;
#pragma unroll
            for (int j = 0; j < 4; ++j) As[m][kk + j] = ldin(A, ab + j, f32);
        }
        {
            int kk = tid >> 4;
            int nn = (tid & 15) * 4;
            size_t bb = zoff + (size_t)(k0 + kk) * PP + n0 + nn;
#pragma unroll
            for (int j = 0; j < 4; ++j)
                Bs[kk][nn + j] = (n0 + nn + j < PP) ? Bm[bb + j] : 0.0f;
        }
        __syncthreads();
#pragma unroll
        for (int kk = 0; kk < 16; ++kk) {
            float a[4], b[4];
#pragma unroll
            for (int i = 0; i < 4; ++i) a[i] = As[ty * 4 + i][kk];
#pragma unroll
            for (int j = 0; j < 4; ++j) b[j] = Bs[kk][tx * 4 + j];
#pragma unroll
            for (int i = 0; i < 4; ++i)
#pragma unroll
                for (int j = 0; j < 4; ++j) acc[i][j] += a[i] * b[j];
        }
        __syncthreads();
    }
#pragma unroll
    for (int i = 0; i < 4; ++i) {
        int m = m0 + ty * 4 + i;
        int bh = blockIdx.z * NHEADS + (m >> 6), d = m & 63;
#pragma unroll
        for (int j = 0; j < 4; ++j) {
            int n = n0 + tx * 4 + j;
            if (n < PP) {
                if (c_mode == 1) Cm[((size_t)bh * PP + n) * HD + d] = f2bf(acc[i][j]);
                else             Cm[((size_t)bh * HD + d) * NKP + n] = f2bf(acc[i][j]);
            }
        }
    }
}

__global__ void zpad_v(short* __restrict__ vtr) {
    int idx = blockIdx.x * blockDim.x + threadIdx.x;
    if (idx >= 64 * 64 * (NKP - PP)) return;
    int bhd = idx / (NKP - PP), nk = PP + idx % (NKP - PP);
    vtr[(size_t)bhd * NKP + nk] = 0;
}

// ---------------- MFMA GEMM: C[z] = A[512][512]bf16 @ Bt[z][n][k]^T, N=4096 ----------------
// global_load_lds staging (linear [128][32] LDS, m97 structure).
// epi 0: plain store [z][m][n] flag dtype; epi 1: qt store bf16 [(z*8+h)][n][d] x0.125
__global__ __launch_bounds__(256)
void gemm_mfma(const short* __restrict__ A, const short* __restrict__ Bt,
               void* __restrict__ Cout, const int* __restrict__ flag, int epi) {
    __shared__ short Alds[128 * 32];
    __shared__ short Blds[128 * 32];
    const int f32 = *flag;
    const int tid = threadIdx.x;
    const int wave = tid >> 6, lane = tid & 63;
    const int quad = lane >> 4, l15 = lane & 15;
    const int wm = wave >> 1, wn = wave & 1;
    const int n0 = blockIdx.x * 128, m0 = blockIdx.y * 128;
    const int z = blockIdx.z;
    const int r4 = tid >> 2;          // 0..63: row within 64-row chunk
    const int s8 = (tid & 3) * 8;     // short offset within 32-short row

    f32x4 acc[4][4];
#pragma unroll
    for (int a = 0; a < 4; ++a)
#pragma unroll
        for (int b = 0; b < 4; ++b) acc[a][b] = (f32x4){0.f, 0.f, 0.f, 0.f};

    const short* abase = A + (size_t)(m0 + r4) * 512 + s8;
    const short* bbase = Bt + ((size_t)z * HW + n0 + r4) * 512 + s8;
    short* al = Alds + r4 * 32 + s8;
    short* bl = Blds + r4 * 32 + s8;

    for (int k0 = 0; k0 < 512; k0 += 32) {
#pragma unroll
        for (int c = 0; c < 2; ++c) {   // A: rows 0..127 in two 64-row chunks
            gload_lds16(abase + (size_t)(c * 64) * 512 + k0, al + c * 2048);
            gload_lds16(bbase + (size_t)(c * 64) * 512 + k0, bl + c * 2048);
        }
        __syncthreads();
        bf16x8 af[4], bfr[4];
#pragma unroll
        for (int a = 0; a < 4; ++a)
            af[a] = *(const bf16x8*)(Alds + (wm * 64 + a * 16 + l15) * 32 + quad * 8);
#pragma unroll
        for (int b = 0; b < 4; ++b)
            bfr[b] = *(const bf16x8*)(Blds + (wn * 64 + b * 16 + l15) * 32 + quad * 8);
#pragma unroll
        for (int a = 0; a < 4; ++a)
#pragma unroll
            for (int b = 0; b < 4; ++b)
                acc[a][b] = __builtin_amdgcn_mfma_f32_16x16x32_bf16(af[a], bfr[b], acc[a][b], 0, 0, 0);
        __syncthreads();
    }
#pragma unroll
    for (int a = 0; a < 4; ++a) {
        int mb = m0 + wm * 64 + a * 16 + quad * 4;
#pragma unroll
        for (int b = 0; b < 4; ++b) {
            int n = n0 + wn * 64 + b * 16 + l15;
            if (epi == 0) {
#pragma unroll
                for (int i = 0; i < 4; ++i)
                    stout(Cout, ((size_t)z * CH + mb + i) * HW + n, acc[a][b][i], f32);
            } else {
                union { alignas(8) short s[4]; int2 v; } u;
#pragma unroll
                for (int i = 0; i < 4; ++i) u.s[i] = f2bf(acc[a][b][i] * 0.125f);
                int h = mb >> 6, d = mb & 63;
                *(int2*)((short*)Cout + ((size_t)(z * NHEADS + h) * HW + n) * HD + d) = u.v;
            }
        }
    }
}

// ---------------- MFMA flash attention ----------------
// qt [64][4096][64] (pre-scaled x0.125), ktr [64][289][64], vtr [64][64][320] (all bf16)
// K and V read directly from global (L2-resident); LDS only for P transpose + O epilogue.
// out attT [8][4096][512] bf16 ([b][pos][c])
__global__ __launch_bounds__(256, 5)
void attn_mfma(const short* __restrict__ qt, const short* __restrict__ ktr,
               const short* __restrict__ vtr, short* __restrict__ attT) {
    __shared__ short Plds[4 * 16 * 40];  // 5120 B
    __shared__ short Olds[64 * 72];      // 9216 B
    const int tid = threadIdx.x;
    const int wave = tid >> 6, lane = tid & 63;
    const int quad = lane >> 4, l15 = lane & 15;
    const int bh = blockIdx.y;
    const int q0 = blockIdx.x * 64;

    // Q fragments (held in regs for whole block)
    bf16x8 qf0, qf1;
    {
        const short* qp = qt + ((size_t)bh * HW + q0 + wave * 16 + l15) * HD + quad * 8;
        qf0 = *(const bf16x8*)qp;
        qf1 = *(const bf16x8*)(qp + 32);
    }

    f32x4 O[4];
#pragma unroll
    for (int df = 0; df < 4; ++df) O[df] = (f32x4){0.f, 0.f, 0.f, 0.f};
    float lsum[4] = {0.f, 0.f, 0.f, 0.f};
    short* pw = Plds + wave * 16 * 40;
    const short* vbase = vtr + (size_t)bh * HD * NKP;
    const short* kbase = ktr + (size_t)bh * PP * HD;

    for (int sc = 0; sc < 10; ++sc) {
        int nk0 = sc * 32;
        f32x4 sf[2];
#pragma unroll
        for (int c2 = 0; c2 < 2; ++c2) {
            int krow = nk0 + c2 * 16 + l15;
            if (krow > PP - 1) krow = PP - 1;   // clamp pad rows (masked below)
            const short* kp = kbase + (size_t)krow * HD + quad * 8;
            bf16x8 kf0 = *(const bf16x8*)kp;
            bf16x8 kf1 = *(const bf16x8*)(kp + 32);
            f32x4 zz = (f32x4){0.f, 0.f, 0.f, 0.f};
            zz = __builtin_amdgcn_mfma_f32_16x16x32_bf16(qf0, kf0, zz, 0, 0, 0);
            sf[c2] = __builtin_amdgcn_mfma_f32_16x16x32_bf16(qf1, kf1, zz, 0, 0, 0);
        }
        // exp (no max-subtraction: |s| small by construction), mask pad, pack P
#pragma unroll
        for (int c2 = 0; c2 < 2; ++c2) {
            int nk = nk0 + c2 * 16 + l15;
            bool valid = nk < PP;
#pragma unroll
            for (int i = 0; i < 4; ++i) {
                float p = valid ? __expf(fminf(sf[c2][i], 30.f)) : 0.f;
                lsum[i] += p;
                pw[(quad * 4 + i) * 40 + c2 * 16 + l15] = f2bf(p);
            }
        }
        // wave-local LDS fence: P writes (scattered lanes) -> A-frag reads
        asm volatile("s_waitcnt lgkmcnt(0)" ::: "memory");
        bf16x8 pf = *(const bf16x8*)(pw + l15 * 40 + quad * 8);
        const short* vp = vbase + nk0 + quad * 8;
#pragma unroll
        for (int df = 0; df < 4; ++df) {
            bf16x8 vf = *(const bf16x8*)(vp + (size_t)(df * 16 + l15) * NKP);
            O[df] = __builtin_amdgcn_mfma_f32_16x16x32_bf16(pf, vf, O[df], 0, 0, 0);
        }
        asm volatile("" ::: "memory");  // keep next iter's P writes after this iter's reads
    }
    // row sums: butterfly over the 16 lanes holding each row group
#pragma unroll
    for (int i = 0; i < 4; ++i) {
        float s = lsum[i];
        s += __shfl_xor(s, 1, 64);
        s += __shfl_xor(s, 2, 64);
        s += __shfl_xor(s, 4, 64);
        s += __shfl_xor(s, 8, 64);
        lsum[i] = 1.0f / s;
    }
    // normalize + transpose O through LDS, store [b][pos][c] coalesced
#pragma unroll
    for (int df = 0; df < 4; ++df)
#pragma unroll
        for (int i = 0; i < 4; ++i)
            Olds[(wave * 16 + quad * 4 + i) * 72 + df * 16 + l15] = f2bf(O[df][i] * lsum[i]);
    __syncthreads();
    {
        int q = tid >> 2, seg = tid & 3;
        int4 a = *(const int4*)(Olds + q * 72 + seg * 16);
        int4 b2 = *(const int4*)(Olds + q * 72 + seg * 16 + 8);
        int b = bh >> 3, h = bh & 7;
        short* op = attT + ((size_t)b * HW + q0 + q) * CH + h * HD + seg * 16;
        *(int4*)op = a;
        *(int4*)(op + 8) = b2;
    }
}

extern "C" void kernel_launch(void* const* d_in, const int* in_sizes, int n_in,
                              void* d_out, int out_size, void* d_ws, size_t ws_size,
                              hipStream_t stream) {
    const void* sem    = d_in[0];
    const void* spa    = d_in[1];
    const void* x      = d_in[2];
    const void* wq     = d_in[3];
    const void* wkv_dw = d_in[4];
    const void* ln_g   = d_in[5];
    const void* ln_b   = d_in[6];
    const void* wkv_pw = d_in[7];
    const void* wout   = d_in[8];

    const size_t nkv = (size_t)BATCH * CH * PP;      // 1,183,744
    char* p = (char*)d_ws;
    auto alloc = [&](size_t bytes) { char* r = p; p += (bytes + 255) & ~(size_t)255; return r; };
    int*   flag  = (int*)alloc(256);
    float* tk    = (float*)alloc(nkv * 4);
    float* tv    = (float*)alloc(nkv * 4);
    short* ktr   = (short*)alloc((size_t)64 * PP * HD * 2);
    short* vtr   = (short*)alloc((size_t)64 * HD * NKP * 2);
    short* semT  = (short*)alloc((size_t)BATCH * HW * CH * 2);
    short* attT  = (short*)alloc((size_t)BATCH * HW * CH * 2);
    short* wqb   = (short*)alloc((size_t)512 * 512 * 2);
    short* woutb = (short*)alloc((size_t)512 * 512 * 2);
    short* qt    = (short*)d_out;   // q staged bf16 in d_out; dead before final gemm

    detect_dtype<<<1, 256, 0, stream>>>((const unsigned short*)sem, flag);

    cvt_w<<<128, 256, 0, stream>>>(wq, wqb, flag);
    cvt_w<<<128, 256, 0, stream>>>(wout, woutb, flag);

    dim3 gt(HW / 64, CH / 64, BATCH);
    transpose_cvt<<<gt, 256, 0, stream>>>(sem, semT, flag);

    dwconv<<<BATCH * CH, 256, 0, stream>>>(spa, wkv_dw, tk, flag);
    dwconv<<<BATCH * CH, 256, 0, stream>>>(x,   wkv_dw, tv, flag);

    lnorm_c<<<BATCH * PP, 256, 0, stream>>>(tk, ln_g, ln_b, flag);
    lnorm_c<<<BATCH * PP, 256, 0, stream>>>(tv, ln_g, ln_b, flag);

    zpad_v<<<(64 * 64 * (NKP - PP) + 255) / 256, 256, 0, stream>>>(vtr);

    dim3 gpw((PP + 63) / 64, CH / 64, BATCH);
    kv_gemm<<<gpw, 256, 0, stream>>>(wkv_pw, tk, ktr, flag, 1);
    kv_gemm<<<gpw, 256, 0, stream>>>(wkv_pw, tv, vtr, flag, 2);

    dim3 gg(HW / 128, CH / 128, BATCH);
    gemm_mfma<<<gg, 256, 0, stream>>>(wqb, semT, qt, flag, 1);

    dim3 ga(HW / 64, 64);
    attn_mfma<<<ga, 256, 0, stream>>>(qt, ktr, vtr, attT);

    gemm_mfma<<<gg, 256, 0, stream>>>(woutb, attT, d_out, flag, 0);
}

// Round 2
// 652.916 us; speedup vs baseline: 1.0859x; 1.0859x over previous
//
#include <hip/hip_runtime.h>
#include <hip/hip_bf16.h>

// S2Attention, dtype-adaptive, MFMA pipeline.
// B=8 C=512 H=W=64 HEADS=8 d=64 R=4 -> k/v spatial 17x17=289 (padded 320).
//
//  0) detect:  flag = externals f32 (1) vs bf16 (0)
//  0b) cvt_w:  wq, wout -> bf16 [512*512] (sanitized)
//  1) transpose_cvt: sem [z][512][4096] -> semT [z][4096][512] bf16
//  2) dwconv:  spa,x -> tk,tv [B,C,289] f32 (plane-tiled, coalesced)
//  3) lnorm_c: channel LayerNorm, in-place f32
//  4) kv gemm (scalar): K -> kpack bf16 [bh][8 dg][320 nk][8 d] (fragment-linear)
//                       V -> vpack bf16 [bh][40 ng][64 d][8 nk] (fragment-linear)
//     (+ zpad_v zeroes pad nk 289..319 in both packs)
//  5) gemm_mfma epi=1: q = wq @ sem -> qt bf16 [64][4096][64] in d_out (x0.125 folded)
//  6) attn_mfma: flash-style, q-tile 128, reg-pipelined, coalesced K/V -> attT bf16
//  7) gemm_mfma epi=0: out = wout @ att -> d_out (flag dtype)

#define BATCH 8
#define CH 512
#define HW 4096
#define NHEADS 8
#define HD 64
#define PP 289
#define NKP 320

typedef __attribute__((ext_vector_type(8))) short bf16x8;
typedef __attribute__((ext_vector_type(4))) float f32x4;

__device__ inline float sanitize(float x) {
    unsigned u = __float_as_uint(x);
    if ((u & 0x7F800000u) == 0x7F800000u) return 0.0f;
    return x;
}
__device__ inline float ldin(const void* p, size_t i, int f32) {
    float x = f32 ? ((const float*)p)[i]
                  : __bfloat162float(((const __hip_bfloat16*)p)[i]);
    return sanitize(x);
}
__device__ inline void stout(void* p, size_t i, float v, int f32) {
    if (f32) ((float*)p)[i] = v;
    else     ((__hip_bfloat16*)p)[i] = __float2bfloat16(v);
}
__device__ inline short f2bf(float x) {   // RNE f32->bf16 (inputs pre-sanitized)
    unsigned u = __float_as_uint(x);
    unsigned r = (u + 0x7FFFu + ((u >> 16) & 1u)) >> 16;
    return (short)r;
}
__device__ inline void gload_lds16(const void* g, void* l) {
    __builtin_amdgcn_global_load_lds(
        (const __attribute__((address_space(1))) void*)g,
        (__attribute__((address_space(3))) void*)l, 16, 0, 0);
}

// ---------------- dtype detector ----------------
__global__ void detect_dtype(const unsigned short* __restrict__ w, int* __restrict__ flag) {
    __shared__ int red[256];
    int tid = threadIdx.x;
    int cnt = 0;
    for (int i = tid; i < 8192; i += 256) {
        unsigned e = w[i] & 0x7F80u;
        cnt += (e >= 0x4300u) ? 1 : 0;
    }
    red[tid] = cnt;
    __syncthreads();
    for (int o = 128; o; o >>= 1) { if (tid < o) red[tid] += red[tid + o]; __syncthreads(); }
    if (tid == 0) *flag = (red[0] > 500) ? 1 : 0;
}

// ---------------- weight convert: [512*512] ext dtype -> bf16 ----------------
__global__ __launch_bounds__(256)
void cvt_w(const void* __restrict__ in, short* __restrict__ out, const int* __restrict__ flag) {
    const int f32 = *flag;
    int i = (blockIdx.x * 256 + threadIdx.x) * 8;
#pragma unroll
    for (int e = 0; e < 8; ++e) out[i + e] = f2bf(ldin(in, i + e, f32));
}

// ---------------- sem transpose+cvt: [z][512][4096] ext -> [z][4096][512] bf16 ----
__global__ __launch_bounds__(256)
void transpose_cvt(const void* __restrict__ in, short* __restrict__ outT,
                   const int* __restrict__ flag) {
    __shared__ short T[64 * 72];
    const int f32 = *flag;
    const int tid = threadIdx.x;
    const int z = blockIdx.z;
    const int c0 = blockIdx.y * 64, p0 = blockIdx.x * 64;
    {
        int c = tid >> 2, ps = (tid & 3) * 16;
        size_t src = ((size_t)z * CH + c0 + c) * HW + p0 + ps;
#pragma unroll
        for (int e = 0; e < 16; ++e)
            T[c * 72 + ps + e] = f2bf(ldin(in, src + e, f32));
    }
    __syncthreads();
    {
        int p = tid >> 2, cs = (tid & 3) * 16;
        union { short s[16]; int4 v[2]; } u;
#pragma unroll
        for (int e = 0; e < 16; ++e) u.s[e] = T[(cs + e) * 72 + p];
        short* op = outT + ((size_t)z * HW + p0 + p) * CH + c0 + cs;
        *(int4*)op = u.v[0];
        *(int4*)(op + 8) = u.v[1];
    }
}

// ---------------- depthwise 4x4 stride4 pad2 conv, plane-tiled ----------------
__global__ __launch_bounds__(256)
void dwconv(const void* __restrict__ in, const void* __restrict__ w,
            float* __restrict__ out, const int* __restrict__ flag) {
    __shared__ float T[4096];
    __shared__ float wf[16];
    const int f32 = *flag;
    const int tid = threadIdx.x;
    const int bc = blockIdx.x;                 // b*CH + c
    const int c = bc & (CH - 1);
    size_t ibase = (size_t)bc * HW;
    if (tid < 16) wf[tid] = ldin(w, (size_t)c * 16 + tid, f32);
#pragma unroll
    for (int k = 0; k < 16; ++k)
        T[tid + k * 256] = ldin(in, ibase + tid + k * 256, f32);
    __syncthreads();
    for (int o = tid; o < PP; o += 256) {
        int oy = o / 17, ox = o % 17;
        float s = 0.f;
#pragma unroll
        for (int ky = 0; ky < 4; ++ky) {
            int iy = oy * 4 - 2 + ky;
            if ((unsigned)iy >= 64u) continue;
#pragma unroll
            for (int kx = 0; kx < 4; ++kx) {
                int ix = ox * 4 - 2 + kx;
                if ((unsigned)ix >= 64u) continue;
                s += T[iy * 64 + ix] * wf[ky * 4 + kx];
            }
        }
        out[(size_t)bc * PP + o] = s;
    }
}

// ---------------- channel LayerNorm (over C=512) ----------------
__global__ __launch_bounds__(256)
void lnorm_c(float* __restrict__ t, const void* __restrict__ g,
             const void* __restrict__ bb, const int* __restrict__ flag) {
    __shared__ float red[256];
    const int f32 = *flag;
    int tid = threadIdx.x;
    int pos = blockIdx.x % PP;
    int b = blockIdx.x / PP;
    float* base = t + (size_t)b * CH * PP + pos;
    int c0 = tid, c1 = tid + 256;
    float v0 = base[(size_t)c0 * PP];
    float v1 = base[(size_t)c1 * PP];
    red[tid] = v0 + v1;
    __syncthreads();
    for (int off = 128; off > 0; off >>= 1) {
        if (tid < off) red[tid] += red[tid + off];
        __syncthreads();
    }
    float mean = red[0] * (1.0f / 512.0f);
    __syncthreads();
    float d0 = v0 - mean, d1 = v1 - mean;
    red[tid] = d0 * d0 + d1 * d1;
    __syncthreads();
    for (int off = 128; off > 0; off >>= 1) {
        if (tid < off) red[tid] += red[tid + off];
        __syncthreads();
    }
    float var = red[0] * (1.0f / 512.0f);
    float rstd = rsqrtf(var + 1e-5f);
    base[(size_t)c0 * PP] = d0 * rstd * ldin(g, c0, f32) + ldin(bb, c0, f32);
    base[(size_t)c1 * PP] = d1 * rstd * ldin(g, c1, f32) + ldin(bb, c1, f32);
}

// ---------------- kv pointwise GEMM (scalar), N=289 ----------------
// c_mode 1: K -> kpack [bh][dg=d>>3][nk][d&7]; c_mode 2: V -> vpack [bh][nk>>3][d][nk&7]
__global__ __launch_bounds__(256)
void kv_gemm(const void* __restrict__ A, const float* __restrict__ Bm,
             short* __restrict__ Cm, const int* __restrict__ flag, int c_mode) {
    __shared__ float As[64][17];
    __shared__ float Bs[16][64];
    const int f32 = *flag;
    const int tid = threadIdx.x;
    const int tx = tid & 15, ty = tid >> 4;
    const int n0 = blockIdx.x * 64;
    const int m0 = blockIdx.y * 64;
    const size_t zoff = (size_t)blockIdx.z * CH * PP;

    float acc[4][4] = {};
    for (int k0 = 0; k0 < CH; k0 += 16) {
        {
            int m = tid >> 2;
            int kk = (tid & 3) * 4;
            size_t ab = (size_t)(m0 + m) * CH + k0 + kk;
#pragma unroll
            for (int j = 0; j < 4; ++j) As[m][kk + j] = ldin(A, ab + j, f32);
        }
        {
            int kk = tid >> 4;
            int nn = (tid & 15) * 4;
            size_t bb = zoff + (size_t)(k0 + kk) * PP + n0 + nn;
#pragma unroll
            for (int j = 0; j < 4; ++j)
                Bs[kk][nn + j] = (n0 + nn + j < PP) ? Bm[bb + j] : 0.0f;
        }
        __syncthreads();
#pragma unroll
        for (int kk = 0; kk < 16; ++kk) {
            float a[4], b[4];
#pragma unroll
            for (int i = 0; i < 4; ++i) a[i] = As[ty * 4 + i][kk];
#pragma unroll
            for (int j = 0; j < 4; ++j) b[j] = Bs[kk][tx * 4 + j];
#pragma unroll
            for (int i = 0; i < 4; ++i)
#pragma unroll
                for (int j = 0; j < 4; ++j) acc[i][j] += a[i] * b[j];
        }
        __syncthreads();
    }
#pragma unroll
    for (int i = 0; i < 4; ++i) {
        int m = m0 + ty * 4 + i;
        int bh = blockIdx.z * NHEADS + (m >> 6), d = m & 63;
#pragma unroll
        for (int j = 0; j < 4; ++j) {
            int n = n0 + tx * 4 + j;
            if (n < PP) {
                if (c_mode == 1)
                    Cm[(((size_t)bh * 8 + (d >> 3)) * NKP + n) * 8 + (d & 7)] = f2bf(acc[i][j]);
                else
                    Cm[(((size_t)bh * 40 + (n >> 3)) * HD + d) * 8 + (n & 7)] = f2bf(acc[i][j]);
            }
        }
    }
}

// zero pad nk 289..319 in kpack (int4 rows) and vpack (scattered shorts)
__global__ void zpad_v(short* __restrict__ kpack, short* __restrict__ vpack) {
    int idx = blockIdx.x * blockDim.x + threadIdx.x;
    const int NKPAD = NKP - PP;                 // 31
    const int KTOT = 64 * 8 * NKPAD;            // 15872 int4 slots
    if (idx < KTOT) {
        int nk = PP + idx % NKPAD;
        int t = idx / NKPAD;
        int dg = t & 7, bh = t >> 3;
        *(int4*)(kpack + (((size_t)bh * 8 + dg) * NKP + nk) * 8) = make_int4(0, 0, 0, 0);
        return;
    }
    int j = idx - KTOT;
    if (j >= 64 * NKPAD * HD) return;
    int bh = j / (NKPAD * HD);
    int r = j % (NKPAD * HD);
    int nk = PP + r / HD;
    int d = r % HD;
    vpack[(((size_t)bh * 40 + (nk >> 3)) * HD + d) * 8 + (nk & 7)] = 0;
}

// ---------------- MFMA GEMM: C[z] = A[512][512]bf16 @ Bt[z][n][k]^T, N=4096 ----------------
// global_load_lds staging (linear [128][32] LDS, m97 structure).
// epi 0: plain store [z][m][n] flag dtype; epi 1: qt store bf16 [(z*8+h)][n][d] x0.125
__global__ __launch_bounds__(256)
void gemm_mfma(const short* __restrict__ A, const short* __restrict__ Bt,
               void* __restrict__ Cout, const int* __restrict__ flag, int epi) {
    __shared__ short Alds[128 * 32];
    __shared__ short Blds[128 * 32];
    const int f32 = *flag;
    const int tid = threadIdx.x;
    const int wave = tid >> 6, lane = tid & 63;
    const int quad = lane >> 4, l15 = lane & 15;
    const int wm = wave >> 1, wn = wave & 1;
    const int n0 = blockIdx.x * 128, m0 = blockIdx.y * 128;
    const int z = blockIdx.z;
    const int r4 = tid >> 2;          // 0..63: row within 64-row chunk
    const int s8 = (tid & 3) * 8;     // short offset within 32-short row

    f32x4 acc[4][4];
#pragma unroll
    for (int a = 0; a < 4; ++a)
#pragma unroll
        for (int b = 0; b < 4; ++b) acc[a][b] = (f32x4){0.f, 0.f, 0.f, 0.f};

    const short* abase = A + (size_t)(m0 + r4) * 512 + s8;
    const short* bbase = Bt + ((size_t)z * HW + n0 + r4) * 512 + s8;
    short* al = Alds + r4 * 32 + s8;
    short* bl = Blds + r4 * 32 + s8;

    for (int k0 = 0; k0 < 512; k0 += 32) {
#pragma unroll
        for (int c = 0; c < 2; ++c) {   // A: rows 0..127 in two 64-row chunks
            gload_lds16(abase + (size_t)(c * 64) * 512 + k0, al + c * 2048);
            gload_lds16(bbase + (size_t)(c * 64) * 512 + k0, bl + c * 2048);
        }
        __syncthreads();
        bf16x8 af[4], bfr[4];
#pragma unroll
        for (int a = 0; a < 4; ++a)
            af[a] = *(const bf16x8*)(Alds + (wm * 64 + a * 16 + l15) * 32 + quad * 8);
#pragma unroll
        for (int b = 0; b < 4; ++b)
            bfr[b] = *(const bf16x8*)(Blds + (wn * 64 + b * 16 + l15) * 32 + quad * 8);
#pragma unroll
        for (int a = 0; a < 4; ++a)
#pragma unroll
            for (int b = 0; b < 4; ++b)
                acc[a][b] = __builtin_amdgcn_mfma_f32_16x16x32_bf16(af[a], bfr[b], acc[a][b], 0, 0, 0);
        __syncthreads();
    }
#pragma unroll
    for (int a = 0; a < 4; ++a) {
        int mb = m0 + wm * 64 + a * 16 + quad * 4;
#pragma unroll
        for (int b = 0; b < 4; ++b) {
            int n = n0 + wn * 64 + b * 16 + l15;
            if (epi == 0) {
#pragma unroll
                for (int i = 0; i < 4; ++i)
                    stout(Cout, ((size_t)z * CH + mb + i) * HW + n, acc[a][b][i], f32);
            } else {
                union { alignas(8) short s[4]; int2 v; } u;
#pragma unroll
                for (int i = 0; i < 4; ++i) u.s[i] = f2bf(acc[a][b][i] * 0.125f);
                int h = mb >> 6, d = mb & 63;
                *(int2*)((short*)Cout + ((size_t)(z * NHEADS + h) * HW + n) * HD + d) = u.v;
            }
        }
    }
}

// ---------------- MFMA flash attention, q-tile 128, pipelined ----------------
// qt [64][4096][64] (pre-scaled x0.125)
// kpack [bh][8][320][8]: K frag-linear; vpack [bh][40][64][8]: V frag-linear (pads zeroed)
// out attT [8][4096][512] bf16 ([b][pos][c])
__global__ __launch_bounds__(256, 3)
void attn_mfma(const short* __restrict__ qt, const short* __restrict__ kpack,
               const short* __restrict__ vpack, short* __restrict__ attT) {
    __shared__ short Plds[4 * 2 * 2 * 640];  // wave x frag x dbuf x [16q][40k] = 20480 B
    __shared__ short Olds[128 * 72];         // 18432 B
    const int tid = threadIdx.x;
    const int wave = tid >> 6, lane = tid & 63;
    const int quad = lane >> 4, l15 = lane & 15;
    const int bh = blockIdx.y;
    const int q0 = blockIdx.x * 128;

    // Q fragments: rows q0 + wave*32 + r*16 + l15, d-chunks quad*8 and 32+quad*8
    bf16x8 qf[2][2];
#pragma unroll
    for (int r = 0; r < 2; ++r) {
        const short* qp = qt + ((size_t)bh * HW + q0 + wave * 32 + r * 16 + l15) * HD + quad * 8;
        qf[r][0] = *(const bf16x8*)qp;
        qf[r][1] = *(const bf16x8*)(qp + 32);
    }

    const short* kbase = kpack + (size_t)bh * 8 * NKP * 8;
    const short* vbase = vpack + (size_t)bh * 40 * HD * 8;

    f32x4 O[2][4];
    float lsum[2][4];
#pragma unroll
    for (int r = 0; r < 2; ++r)
#pragma unroll
        for (int df = 0; df < 4; ++df) {
            O[r][df] = (f32x4){0.f, 0.f, 0.f, 0.f};
            lsum[r][df] = 0.f;
        }

    // K register double-buffer; preload sc=0
    bf16x8 kf[2][4];
#pragma unroll
    for (int c2 = 0; c2 < 2; ++c2) {
        kf[0][c2 * 2 + 0] = *(const bf16x8*)(kbase + ((size_t)quad * NKP + c2 * 16 + l15) * 8);
        kf[0][c2 * 2 + 1] = *(const bf16x8*)(kbase + ((size_t)(4 + quad) * NKP + c2 * 16 + l15) * 8);
    }

#pragma unroll
    for (int sc = 0; sc < 10; ++sc) {
        const int cur = sc & 1, nxt = cur ^ 1;
        // V for this iteration: coalesced 256B/quad, latency hidden under S+exp phase
        bf16x8 vf[4];
#pragma unroll
        for (int df = 0; df < 4; ++df)
            vf[df] = *(const bf16x8*)(vbase + (((size_t)(sc * 4 + quad)) * HD + df * 16 + l15) * 8);
        // prefetch next iteration's K fragments
        if (sc < 9) {
#pragma unroll
            for (int c2 = 0; c2 < 2; ++c2) {
                kf[nxt][c2 * 2 + 0] = *(const bf16x8*)(kbase + ((size_t)quad * NKP + (sc + 1) * 32 + c2 * 16 + l15) * 8);
                kf[nxt][c2 * 2 + 1] = *(const bf16x8*)(kbase + ((size_t)(4 + quad) * NKP + (sc + 1) * 32 + c2 * 16 + l15) * 8);
            }
        }
        // S = QK^T, exp, pack P into per-wave double-buffered LDS tile
#pragma unroll
        for (int r = 0; r < 2; ++r) {
            short* pw = Plds + (((wave * 2 + r) * 2 + cur) * 640);
#pragma unroll
            for (int c2 = 0; c2 < 2; ++c2) {
                f32x4 zz = (f32x4){0.f, 0.f, 0.f, 0.f};
                zz = __builtin_amdgcn_mfma_f32_16x16x32_bf16(qf[r][0], kf[cur][c2 * 2 + 0], zz, 0, 0, 0);
                f32x4 sfv = __builtin_amdgcn_mfma_f32_16x16x32_bf16(qf[r][1], kf[cur][c2 * 2 + 1], zz, 0, 0, 0);
                int nk = sc * 32 + c2 * 16 + l15;
                bool valid = nk < PP;
#pragma unroll
                for (int i = 0; i < 4; ++i) {
                    float pv = valid ? __expf(fminf(sfv[i], 30.f)) : 0.f;
                    lsum[r][i] += pv;
                    pw[(quad * 4 + i) * 40 + c2 * 16 + l15] = f2bf(pv);
                }
            }
        }
        // wave-local fence: P writes -> A-frag reads (LDS only; global prefetch unaffected)
        asm volatile("s_waitcnt lgkmcnt(0)" ::: "memory");
        __builtin_amdgcn_sched_barrier(0);
#pragma unroll
        for (int r = 0; r < 2; ++r) {
            const short* pw = Plds + (((wave * 2 + r) * 2 + cur) * 640);
            bf16x8 pf = *(const bf16x8*)(pw + l15 * 40 + quad * 8);
#pragma unroll
            for (int df = 0; df < 4; ++df)
                O[r][df] = __builtin_amdgcn_mfma_f32_16x16x32_bf16(pf, vf[df], O[r][df], 0, 0, 0);
        }
        // no trailing fence: next iter writes the other P buffer (reg dbuf breaks WAR)
    }
    // row sums: butterfly over the 16 lanes holding each row group
#pragma unroll
    for (int r = 0; r < 2; ++r)
#pragma unroll
        for (int i = 0; i < 4; ++i) {
            float s = lsum[r][i];
            s += __shfl_xor(s, 1, 64);
            s += __shfl_xor(s, 2, 64);
            s += __shfl_xor(s, 4, 64);
            s += __shfl_xor(s, 8, 64);
            lsum[r][i] = 1.0f / s;
        }
    // normalize + transpose O through LDS, store [b][pos][c] coalesced
#pragma unroll
    for (int r = 0; r < 2; ++r)
#pragma unroll
        for (int df = 0; df < 4; ++df)
#pragma unroll
            for (int i = 0; i < 4; ++i)
                Olds[(wave * 32 + r * 16 + quad * 4 + i) * 72 + df * 16 + l15] = f2bf(O[r][df][i] * lsum[r][i]);
    __syncthreads();
    {
        int q = tid >> 1, half = tid & 1;
        const short* src = Olds + q * 72 + half * 32;
        int4 a0 = *(const int4*)(src);
        int4 a1 = *(const int4*)(src + 8);
        int4 a2 = *(const int4*)(src + 16);
        int4 a3 = *(const int4*)(src + 24);
        int b = bh >> 3, h = bh & 7;
        short* op = attT + ((size_t)b * HW + q0 + q) * CH + h * HD + half * 32;
        *(int4*)op = a0;
        *(int4*)(op + 8) = a1;
        *(int4*)(op + 16) = a2;
        *(int4*)(op + 24) = a3;
    }
}

extern "C" void kernel_launch(void* const* d_in, const int* in_sizes, int n_in,
                              void* d_out, int out_size, void* d_ws, size_t ws_size,
                              hipStream_t stream) {
    const void* sem    = d_in[0];
    const void* spa    = d_in[1];
    const void* x      = d_in[2];
    const void* wq     = d_in[3];
    const void* wkv_dw = d_in[4];
    const void* ln_g   = d_in[5];
    const void* ln_b   = d_in[6];
    const void* wkv_pw = d_in[7];
    const void* wout   = d_in[8];

    const size_t nkv = (size_t)BATCH * CH * PP;      // 1,183,744
    char* p = (char*)d_ws;
    auto alloc = [&](size_t bytes) { char* r = p; p += (bytes + 255) & ~(size_t)255; return r; };
    int*   flag  = (int*)alloc(256);
    float* tk    = (float*)alloc(nkv * 4);
    float* tv    = (float*)alloc(nkv * 4);
    short* kpk   = (short*)alloc((size_t)64 * 8 * NKP * 8 * 2);    // 2.62 MB
    short* vpk   = (short*)alloc((size_t)64 * 40 * HD * 8 * 2);    // 2.62 MB
    short* semT  = (short*)alloc((size_t)BATCH * HW * CH * 2);
    short* attT  = (short*)alloc((size_t)BATCH * HW * CH * 2);
    short* wqb   = (short*)alloc((size_t)512 * 512 * 2);
    short* woutb = (short*)alloc((size_t)512 * 512 * 2);
    short* qt    = (short*)d_out;   // q staged bf16 in d_out; dead before final gemm

    detect_dtype<<<1, 256, 0, stream>>>((const unsigned short*)sem, flag);

    cvt_w<<<128, 256, 0, stream>>>(wq, wqb, flag);
    cvt_w<<<128, 256, 0, stream>>>(wout, woutb, flag);

    dim3 gt(HW / 64, CH / 64, BATCH);
    transpose_cvt<<<gt, 256, 0, stream>>>(sem, semT, flag);

    dwconv<<<BATCH * CH, 256, 0, stream>>>(spa, wkv_dw, tk, flag);
    dwconv<<<BATCH * CH, 256, 0, stream>>>(x,   wkv_dw, tv, flag);

    lnorm_c<<<BATCH * PP, 256, 0, stream>>>(tk, ln_g, ln_b, flag);
    lnorm_c<<<BATCH * PP, 256, 0, stream>>>(tv, ln_g, ln_b, flag);

    {
        int ztot = 64 * 8 * (NKP - PP) + 64 * (NKP - PP) * HD;
        zpad_v<<<(ztot + 255) / 256, 256, 0, stream>>>(kpk, vpk);
    }

    dim3 gpw((PP + 63) / 64, CH / 64, BATCH);
    kv_gemm<<<gpw, 256, 0, stream>>>(wkv_pw, tk, kpk, flag, 1);
    kv_gemm<<<gpw, 256, 0, stream>>>(wkv_pw, tv, vpk, flag, 2);

    dim3 gg(HW / 128, CH / 128, BATCH);
    gemm_mfma<<<gg, 256, 0, stream>>>(wqb, semT, qt, flag, 1);

    dim3 ga(HW / 128, 64);
    attn_mfma<<<ga, 256, 0, stream>>>(qt, kpk, vpk, attT);

    gemm_mfma<<<gg, 256, 0, stream>>>(woutb, attT, d_out, flag, 0);
}

// Round 3
// 563.446 us; speedup vs baseline: 1.2584x; 1.1588x over previous
//
#include <hip/hip_runtime.h>
#include <hip/hip_bf16.h>

// S2Attention, dtype-adaptive, MFMA pipeline.
// B=8 C=512 H=W=64 HEADS=8 d=64 R=4 -> k/v spatial 17x17=289 (padded 320).
//
//  0) detect:  flag = externals f32 (1) vs bf16 (0)
//  0b) cvt_w:  wq, wout -> bf16 [512*512] (sanitized)
//  1) transpose_cvt: sem [z][512][4096] -> semT [z][4096][512] bf16 (vectorized)
//  2) dwconv:  spa,x -> tk,tv [B,C,289] f32 (plane-tiled, vectorized staging)
//  3) lnorm_c: channel LayerNorm, in-place f32
//  4) kv gemm (scalar): K -> kpack bf16 [bh][8 dg][320 nk][8 d] (fragment-linear)
//                       V -> vpack bf16 [bh][40 ng][64 d][8 nk] (fragment-linear)
//     (+ zpad_v zeroes pad nk 289..319 in both packs)
//  5) gemm_mfma epi=1: q = wq @ sem -> qt bf16 [64][4096][64] in d_out (x0.125 folded)
//  6) attn_mfma: 512 thr, K/V staged in LDS once, 512 q-rows/block -> attT bf16
//  7) gemm_mfma epi=0: out = wout @ att -> d_out (flag dtype)

#define BATCH 8
#define CH 512
#define HW 4096
#define NHEADS 8
#define HD 64
#define PP 289
#define NKP 320

typedef __attribute__((ext_vector_type(8))) short bf16x8;
typedef __attribute__((ext_vector_type(4))) float f32x4;

__device__ inline float sanitize(float x) {
    unsigned u = __float_as_uint(x);
    if ((u & 0x7F800000u) == 0x7F800000u) return 0.0f;
    return x;
}
__device__ inline float ldin(const void* p, size_t i, int f32) {
    float x = f32 ? ((const float*)p)[i]
                  : __bfloat162float(((const __hip_bfloat16*)p)[i]);
    return sanitize(x);
}
__device__ inline void stout(void* p, size_t i, float v, int f32) {
    if (f32) ((float*)p)[i] = v;
    else     ((__hip_bfloat16*)p)[i] = __float2bfloat16(v);
}
__device__ inline short f2bf(float x) {   // RNE f32->bf16 (inputs pre-sanitized)
    unsigned u = __float_as_uint(x);
    unsigned r = (u + 0x7FFFu + ((u >> 16) & 1u)) >> 16;
    return (short)r;
}
__device__ inline void gload_lds16(const void* g, void* l) {
    __builtin_amdgcn_global_load_lds(
        (const __attribute__((address_space(1))) void*)g,
        (__attribute__((address_space(3))) void*)l, 16, 0, 0);
}

// ---------------- dtype detector ----------------
__global__ void detect_dtype(const unsigned short* __restrict__ w, int* __restrict__ flag) {
    __shared__ int red[256];
    int tid = threadIdx.x;
    int cnt = 0;
    for (int i = tid; i < 8192; i += 256) {
        unsigned e = w[i] & 0x7F80u;
        cnt += (e >= 0x4300u) ? 1 : 0;
    }
    red[tid] = cnt;
    __syncthreads();
    for (int o = 128; o; o >>= 1) { if (tid < o) red[tid] += red[tid + o]; __syncthreads(); }
    if (tid == 0) *flag = (red[0] > 500) ? 1 : 0;
}

// ---------------- weight convert: [512*512] ext dtype -> bf16 ----------------
__global__ __launch_bounds__(256)
void cvt_w(const void* __restrict__ in, short* __restrict__ out, const int* __restrict__ flag) {
    const int f32 = *flag;
    int i = (blockIdx.x * 256 + threadIdx.x) * 8;
#pragma unroll
    for (int e = 0; e < 8; ++e) out[i + e] = f2bf(ldin(in, i + e, f32));
}

// ---------------- sem transpose+cvt: [z][512][4096] ext -> [z][4096][512] bf16 ----
__global__ __launch_bounds__(256)
void transpose_cvt(const void* __restrict__ in, short* __restrict__ outT,
                   const int* __restrict__ flag) {
    __shared__ short T[64 * 72];
    const int f32 = *flag;
    const int tid = threadIdx.x;
    const int z = blockIdx.z;
    const int c0 = blockIdx.y * 64, p0 = blockIdx.x * 64;
    {
        int c = tid >> 2, ps = (tid & 3) * 16;
        size_t src = ((size_t)z * CH + c0 + c) * HW + p0 + ps;
        short* dst = &T[c * 72 + ps];
        if (f32) {
            const float4* fp = (const float4*)((const float*)in + src);
#pragma unroll
            for (int v = 0; v < 4; ++v) {
                float4 w4 = fp[v];
                dst[v * 4 + 0] = f2bf(sanitize(w4.x));
                dst[v * 4 + 1] = f2bf(sanitize(w4.y));
                dst[v * 4 + 2] = f2bf(sanitize(w4.z));
                dst[v * 4 + 3] = f2bf(sanitize(w4.w));
            }
        } else {
            const int4* ip = (const int4*)((const short*)in + src);
#pragma unroll
            for (int v = 0; v < 2; ++v) {
                union { int4 q; short s[8]; } u; u.q = ip[v];
#pragma unroll
                for (int e = 0; e < 8; ++e) {
                    short sv = u.s[e];
                    if ((sv & 0x7F80) == 0x7F80) sv = 0;
                    dst[v * 8 + e] = sv;
                }
            }
        }
    }
    __syncthreads();
    {
        int p = tid >> 2, cs = (tid & 3) * 16;
        union { short s[16]; int4 v[2]; } u;
#pragma unroll
        for (int e = 0; e < 16; ++e) u.s[e] = T[(cs + e) * 72 + p];
        short* op = outT + ((size_t)z * HW + p0 + p) * CH + c0 + cs;
        *(int4*)op = u.v[0];
        *(int4*)(op + 8) = u.v[1];
    }
}

// ---------------- depthwise 4x4 stride4 pad2 conv, plane-tiled ----------------
__global__ __launch_bounds__(256)
void dwconv(const void* __restrict__ in, const void* __restrict__ w,
            float* __restrict__ out, const int* __restrict__ flag) {
    __shared__ float T[4096];
    __shared__ float wf[16];
    const int f32 = *flag;
    const int tid = threadIdx.x;
    const int bc = blockIdx.x;                 // b*CH + c
    const int c = bc & (CH - 1);
    size_t ibase = (size_t)bc * HW;
    if (tid < 16) wf[tid] = ldin(w, (size_t)c * 16 + tid, f32);
    if (f32) {
        const float4* ip = (const float4*)((const float*)in + ibase);
#pragma unroll
        for (int k = 0; k < 4; ++k) {
            float4 v = ip[k * 256 + tid];
            float* d = &T[(k * 256 + tid) * 4];
            d[0] = sanitize(v.x); d[1] = sanitize(v.y);
            d[2] = sanitize(v.z); d[3] = sanitize(v.w);
        }
    } else {
        const int4* ip = (const int4*)((const short*)in + ibase);
#pragma unroll
        for (int k = 0; k < 2; ++k) {
            union { int4 q; unsigned short s[8]; } u; u.q = ip[k * 256 + tid];
            float* d = &T[(k * 256 + tid) * 8];
#pragma unroll
            for (int e = 0; e < 8; ++e) {
                unsigned short sv = u.s[e];
                if ((sv & 0x7F80u) == 0x7F80u) sv = 0;
                d[e] = __bfloat162float(*(__hip_bfloat16*)&sv);
            }
        }
    }
    __syncthreads();
    for (int o = tid; o < PP; o += 256) {
        int oy = o / 17, ox = o % 17;
        float s = 0.f;
#pragma unroll
        for (int ky = 0; ky < 4; ++ky) {
            int iy = oy * 4 - 2 + ky;
            if ((unsigned)iy >= 64u) continue;
#pragma unroll
            for (int kx = 0; kx < 4; ++kx) {
                int ix = ox * 4 - 2 + kx;
                if ((unsigned)ix >= 64u) continue;
                s += T[iy * 64 + ix] * wf[ky * 4 + kx];
            }
        }
        out[(size_t)bc * PP + o] = s;
    }
}

// ---------------- channel LayerNorm (over C=512) ----------------
__global__ __launch_bounds__(256)
void lnorm_c(float* __restrict__ t, const void* __restrict__ g,
             const void* __restrict__ bb, const int* __restrict__ flag) {
    __shared__ float red[256];
    const int f32 = *flag;
    int tid = threadIdx.x;
    int pos = blockIdx.x % PP;
    int b = blockIdx.x / PP;
    float* base = t + (size_t)b * CH * PP + pos;
    int c0 = tid, c1 = tid + 256;
    float v0 = base[(size_t)c0 * PP];
    float v1 = base[(size_t)c1 * PP];
    red[tid] = v0 + v1;
    __syncthreads();
    for (int off = 128; off > 0; off >>= 1) {
        if (tid < off) red[tid] += red[tid + off];
        __syncthreads();
    }
    float mean = red[0] * (1.0f / 512.0f);
    __syncthreads();
    float d0 = v0 - mean, d1 = v1 - mean;
    red[tid] = d0 * d0 + d1 * d1;
    __syncthreads();
    for (int off = 128; off > 0; off >>= 1) {
        if (tid < off) red[tid] += red[tid + off];
        __syncthreads();
    }
    float var = red[0] * (1.0f / 512.0f);
    float rstd = rsqrtf(var + 1e-5f);
    base[(size_t)c0 * PP] = d0 * rstd * ldin(g, c0, f32) + ldin(bb, c0, f32);
    base[(size_t)c1 * PP] = d1 * rstd * ldin(g, c1, f32) + ldin(bb, c1, f32);
}

// ---------------- kv pointwise GEMM (scalar), N=289 ----------------
// c_mode 1: K -> kpack [bh][dg=d>>3][nk][d&7]; c_mode 2: V -> vpack [bh][nk>>3][d][nk&7]
__global__ __launch_bounds__(256)
void kv_gemm(const void* __restrict__ A, const float* __restrict__ Bm,
             short* __restrict__ Cm, const int* __restrict__ flag, int c_mode) {
    __shared__ float As[64][17];
    __shared__ float Bs[16][64];
    const int f32 = *flag;
    const int tid = threadIdx.x;
    const int tx = tid & 15, ty = tid >> 4;
    const int n0 = blockIdx.x * 64;
    const int m0 = blockIdx.y * 64;
    const size_t zoff = (size_t)blockIdx.z * CH * PP;

    float acc[4][4] = {};
    for (int k0 = 0; k0 < CH; k0 += 16) {
        {
            int m = tid >> 2;
            int kk = (tid & 3) * 4;
            size_t ab = (size_t)(m0 + m) * CH + k0 + kk;
#pragma unroll
            for (int j = 0; j < 4; ++j) As[m][kk + j] = ldin(A, ab + j, f32);
        }
        {
            int kk = tid >> 4;
            int nn = (tid & 15) * 4;
            size_t bb = zoff + (size_t)(k0 + kk) * PP + n0 + nn;
#pragma unroll
            for (int j = 0; j < 4; ++j)
                Bs[kk][nn + j] = (n0 + nn + j < PP) ? Bm[bb + j] : 0.0f;
        }
        __syncthreads();
#pragma unroll
        for (int kk = 0; kk < 16; ++kk) {
            float a[4], b[4];
#pragma unroll
            for (int i = 0; i < 4; ++i) a[i] = As[ty * 4 + i][kk];
#pragma unroll
            for (int j = 0; j < 4; ++j) b[j] = Bs[kk][tx * 4 + j];
#pragma unroll
            for (int i = 0; i < 4; ++i)
#pragma unroll
                for (int j = 0; j < 4; ++j) acc[i][j] += a[i] * b[j];
        }
        __syncthreads();
    }
#pragma unroll
    for (int i = 0; i < 4; ++i) {
        int m = m0 + ty * 4 + i;
        int bh = blockIdx.z * NHEADS + (m >> 6), d = m & 63;
#pragma unroll
        for (int j = 0; j < 4; ++j) {
            int n = n0 + tx * 4 + j;
            if (n < PP) {
                if (c_mode == 1)
                    Cm[(((size_t)bh * 8 + (d >> 3)) * NKP + n) * 8 + (d & 7)] = f2bf(acc[i][j]);
                else
                    Cm[(((size_t)bh * 40 + (n >> 3)) * HD + d) * 8 + (n & 7)] = f2bf(acc[i][j]);
            }
        }
    }
}

// zero pad nk 289..319 in kpack (int4 rows) and vpack (scattered shorts)
__global__ void zpad_v(short* __restrict__ kpack, short* __restrict__ vpack) {
    int idx = blockIdx.x * blockDim.x + threadIdx.x;
    const int NKPAD = NKP - PP;                 // 31
    const int KTOT = 64 * 8 * NKPAD;            // 15872 int4 slots
    if (idx < KTOT) {
        int nk = PP + idx % NKPAD;
        int t = idx / NKPAD;
        int dg = t & 7, bh = t >> 3;
        *(int4*)(kpack + (((size_t)bh * 8 + dg) * NKP + nk) * 8) = make_int4(0, 0, 0, 0);
        return;
    }
    int j = idx - KTOT;
    if (j >= 64 * NKPAD * HD) return;
    int bh = j / (NKPAD * HD);
    int r = j % (NKPAD * HD);
    int nk = PP + r / HD;
    int d = r % HD;
    vpack[(((size_t)bh * 40 + (nk >> 3)) * HD + d) * 8 + (nk & 7)] = 0;
}

// ---------------- MFMA GEMM: C[z] = A[512][512]bf16 @ Bt[z][n][k]^T, N=4096 ----------------
// global_load_lds staging (linear [128][32] LDS, m97 structure).
// epi 0: plain store [z][m][n] flag dtype; epi 1: qt store bf16 [(z*8+h)][n][d] x0.125
__global__ __launch_bounds__(256)
void gemm_mfma(const short* __restrict__ A, const short* __restrict__ Bt,
               void* __restrict__ Cout, const int* __restrict__ flag, int epi) {
    __shared__ short Alds[128 * 32];
    __shared__ short Blds[128 * 32];
    const int f32 = *flag;
    const int tid = threadIdx.x;
    const int wave = tid >> 6, lane = tid & 63;
    const int quad = lane >> 4, l15 = lane & 15;
    const int wm = wave >> 1, wn = wave & 1;
    const int n0 = blockIdx.x * 128, m0 = blockIdx.y * 128;
    const int z = blockIdx.z;
    const int r4 = tid >> 2;          // 0..63: row within 64-row chunk
    const int s8 = (tid & 3) * 8;     // short offset within 32-short row

    f32x4 acc[4][4];
#pragma unroll
    for (int a = 0; a < 4; ++a)
#pragma unroll
        for (int b = 0; b < 4; ++b) acc[a][b] = (f32x4){0.f, 0.f, 0.f, 0.f};

    const short* abase = A + (size_t)(m0 + r4) * 512 + s8;
    const short* bbase = Bt + ((size_t)z * HW + n0 + r4) * 512 + s8;
    short* al = Alds + r4 * 32 + s8;
    short* bl = Blds + r4 * 32 + s8;

    for (int k0 = 0; k0 < 512; k0 += 32) {
#pragma unroll
        for (int c = 0; c < 2; ++c) {   // A: rows 0..127 in two 64-row chunks
            gload_lds16(abase + (size_t)(c * 64) * 512 + k0, al + c * 2048);
            gload_lds16(bbase + (size_t)(c * 64) * 512 + k0, bl + c * 2048);
        }
        __syncthreads();
        bf16x8 af[4], bfr[4];
#pragma unroll
        for (int a = 0; a < 4; ++a)
            af[a] = *(const bf16x8*)(Alds + (wm * 64 + a * 16 + l15) * 32 + quad * 8);
#pragma unroll
        for (int b = 0; b < 4; ++b)
            bfr[b] = *(const bf16x8*)(Blds + (wn * 64 + b * 16 + l15) * 32 + quad * 8);
#pragma unroll
        for (int a = 0; a < 4; ++a)
#pragma unroll
            for (int b = 0; b < 4; ++b)
                acc[a][b] = __builtin_amdgcn_mfma_f32_16x16x32_bf16(af[a], bfr[b], acc[a][b], 0, 0, 0);
        __syncthreads();
    }
#pragma unroll
    for (int a = 0; a < 4; ++a) {
        int mb = m0 + wm * 64 + a * 16 + quad * 4;
#pragma unroll
        for (int b = 0; b < 4; ++b) {
            int n = n0 + wn * 64 + b * 16 + l15;
            if (epi == 0) {
#pragma unroll
                for (int i = 0; i < 4; ++i)
                    stout(Cout, ((size_t)z * CH + mb + i) * HW + n, acc[a][b][i], f32);
            } else {
                union { alignas(8) short s[4]; int2 v; } u;
#pragma unroll
                for (int i = 0; i < 4; ++i) u.s[i] = f2bf(acc[a][b][i] * 0.125f);
                int h = mb >> 6, d = mb & 63;
                *(int2*)((short*)Cout + ((size_t)(z * NHEADS + h) * HW + n) * HD + d) = u.v;
            }
        }
    }
}

// ---------------- MFMA flash attention: K/V staged in LDS, 512 q-rows/block ----
// qt [64][4096][64] (pre-scaled x0.125)
// kpack [bh][8][320][8]: K frag-linear; vpack [bh][40][64][8]: V frag-linear (pads zeroed)
// out attT [8][4096][512] bf16 ([b][pos][c])
__global__ __launch_bounds__(512, 2)
void attn_mfma(const short* __restrict__ qt, const short* __restrict__ kpack,
               const short* __restrict__ vpack, short* __restrict__ attT) {
    __shared__ short Klds[8 * NKP * 8];   // 40960 B, linear copy of kpack head block
    __shared__ short Vlds[40 * HD * 8];   // 40960 B, linear copy of vpack head block
    __shared__ short PO[256 * 72];        // 36864 B: P tiles (loop) / O transpose (epi)
    const int tid = threadIdx.x;
    const int wave = tid >> 6, lane = tid & 63;
    const int quad = lane >> 4, l15 = lane & 15;
    const int bh = blockIdx.y;

    // stage K and V once per block (coalesced 16B direct-to-LDS)
    {
        const short* kbase = kpack + (size_t)bh * 8 * NKP * 8;
        const short* vbase = vpack + (size_t)bh * 40 * HD * 8;
#pragma unroll
        for (int rnd = 0; rnd < 5; ++rnd) {
            int off = (rnd * 512 + tid) * 8;
            gload_lds16(kbase + off, Klds + off);
            gload_lds16(vbase + off, Vlds + off);
        }
    }
    __syncthreads();

    short* pw = PO + (wave * 2) * 640;   // per-wave P tiles: [r][16q][40k]

    for (int it = 0; it < 2; ++it) {
        const int q0 = blockIdx.x * 512 + it * 256;
        // Q fragments: rows q0 + wave*32 + r*16 + l15, d-chunks quad*8 / 32+quad*8
        bf16x8 qf[2][2];
#pragma unroll
        for (int r = 0; r < 2; ++r) {
            const short* qp = qt + ((size_t)bh * HW + q0 + wave * 32 + r * 16 + l15) * HD + quad * 8;
            qf[r][0] = *(const bf16x8*)qp;
            qf[r][1] = *(const bf16x8*)(qp + 32);
        }
        f32x4 O[2][4];
        float lsum[2][4];
#pragma unroll
        for (int r = 0; r < 2; ++r)
#pragma unroll
            for (int df = 0; df < 4; ++df) {
                O[r][df] = (f32x4){0.f, 0.f, 0.f, 0.f};
                lsum[r][df] = 0.f;
            }

#pragma unroll
        for (int sc = 0; sc < 10; ++sc) {
            // K fragments from LDS (shared across r)
            bf16x8 kf0[2], kf1[2], vf[4];
#pragma unroll
            for (int c2 = 0; c2 < 2; ++c2) {
                const short* kp = Klds + ((size_t)quad * NKP + sc * 32 + c2 * 16 + l15) * 8;
                kf0[c2] = *(const bf16x8*)kp;
                kf1[c2] = *(const bf16x8*)(Klds + ((size_t)(4 + quad) * NKP + sc * 32 + c2 * 16 + l15) * 8);
            }
#pragma unroll
            for (int df = 0; df < 4; ++df)
                vf[df] = *(const bf16x8*)(Vlds + (((size_t)(sc * 4 + quad)) * HD + df * 16 + l15) * 8);
            // S = QK^T, exp, pack P (single-buffered per-wave tile; same-wave DS is in-order)
#pragma unroll
            for (int r = 0; r < 2; ++r) {
                short* pwr = pw + r * 640;
#pragma unroll
                for (int c2 = 0; c2 < 2; ++c2) {
                    f32x4 zz = (f32x4){0.f, 0.f, 0.f, 0.f};
                    zz = __builtin_amdgcn_mfma_f32_16x16x32_bf16(qf[r][0], kf0[c2], zz, 0, 0, 0);
                    f32x4 sfv = __builtin_amdgcn_mfma_f32_16x16x32_bf16(qf[r][1], kf1[c2], zz, 0, 0, 0);
                    int nk = sc * 32 + c2 * 16 + l15;
                    bool valid = nk < PP;
#pragma unroll
                    for (int i = 0; i < 4; ++i) {
                        float pv = valid ? __expf(fminf(sfv[i], 30.f)) : 0.f;
                        lsum[r][i] += pv;
                        pwr[(quad * 4 + i) * 40 + c2 * 16 + l15] = f2bf(pv);
                    }
                }
            }
            // RAW fence: P writes -> A-frag reads (wave-local)
            asm volatile("s_waitcnt lgkmcnt(0)" ::: "memory");
            __builtin_amdgcn_sched_barrier(0);
#pragma unroll
            for (int r = 0; r < 2; ++r) {
                bf16x8 pf = *(const bf16x8*)(pw + r * 640 + l15 * 40 + quad * 8);
#pragma unroll
                for (int df = 0; df < 4; ++df)
                    O[r][df] = __builtin_amdgcn_mfma_f32_16x16x32_bf16(pf, vf[df], O[r][df], 0, 0, 0);
            }
            asm volatile("" ::: "memory");  // keep next iter's P writes after these reads
        }
        // row sums
#pragma unroll
        for (int r = 0; r < 2; ++r)
#pragma unroll
            for (int i = 0; i < 4; ++i) {
                float s = lsum[r][i];
                s += __shfl_xor(s, 1, 64);
                s += __shfl_xor(s, 2, 64);
                s += __shfl_xor(s, 4, 64);
                s += __shfl_xor(s, 8, 64);
                lsum[r][i] = 1.0f / s;
            }
        __syncthreads();   // all waves done with P region before O overwrites PO
        // normalize + transpose O through PO, store [b][pos][c] coalesced
#pragma unroll
        for (int r = 0; r < 2; ++r)
#pragma unroll
            for (int df = 0; df < 4; ++df)
#pragma unroll
                for (int i = 0; i < 4; ++i)
                    PO[(wave * 32 + r * 16 + quad * 4 + i) * 72 + df * 16 + l15] =
                        f2bf(O[r][df][i] * lsum[r][i]);
        __syncthreads();
        {
            int q = tid >> 1, half = tid & 1;
            const short* src = PO + q * 72 + half * 32;
            int4 a0 = *(const int4*)(src);
            int4 a1 = *(const int4*)(src + 8);
            int4 a2 = *(const int4*)(src + 16);
            int4 a3 = *(const int4*)(src + 24);
            int b = bh >> 3, h = bh & 7;
            short* op = attT + ((size_t)b * HW + q0 + q) * CH + h * HD + half * 32;
            *(int4*)op = a0;
            *(int4*)(op + 8) = a1;
            *(int4*)(op + 16) = a2;
            *(int4*)(op + 24) = a3;
        }
        __syncthreads();   // PO O-region reads done before next subtile's P writes
    }
}

extern "C" void kernel_launch(void* const* d_in, const int* in_sizes, int n_in,
                              void* d_out, int out_size, void* d_ws, size_t ws_size,
                              hipStream_t stream) {
    const void* sem    = d_in[0];
    const void* spa    = d_in[1];
    const void* x      = d_in[2];
    const void* wq     = d_in[3];
    const void* wkv_dw = d_in[4];
    const void* ln_g   = d_in[5];
    const void* ln_b   = d_in[6];
    const void* wkv_pw = d_in[7];
    const void* wout   = d_in[8];

    const size_t nkv = (size_t)BATCH * CH * PP;      // 1,183,744
    char* p = (char*)d_ws;
    auto alloc = [&](size_t bytes) { char* r = p; p += (bytes + 255) & ~(size_t)255; return r; };
    int*   flag  = (int*)alloc(256);
    float* tk    = (float*)alloc(nkv * 4);
    float* tv    = (float*)alloc(nkv * 4);
    short* kpk   = (short*)alloc((size_t)64 * 8 * NKP * 8 * 2);    // 2.62 MB
    short* vpk   = (short*)alloc((size_t)64 * 40 * HD * 8 * 2);    // 2.62 MB
    short* semT  = (short*)alloc((size_t)BATCH * HW * CH * 2);
    short* attT  = (short*)alloc((size_t)BATCH * HW * CH * 2);
    short* wqb   = (short*)alloc((size_t)512 * 512 * 2);
    short* woutb = (short*)alloc((size_t)512 * 512 * 2);
    short* qt    = (short*)d_out;   // q staged bf16 in d_out; dead before final gemm

    detect_dtype<<<1, 256, 0, stream>>>((const unsigned short*)sem, flag);

    cvt_w<<<128, 256, 0, stream>>>(wq, wqb, flag);
    cvt_w<<<128, 256, 0, stream>>>(wout, woutb, flag);

    dim3 gt(HW / 64, CH / 64, BATCH);
    transpose_cvt<<<gt, 256, 0, stream>>>(sem, semT, flag);

    dwconv<<<BATCH * CH, 256, 0, stream>>>(spa, wkv_dw, tk, flag);
    dwconv<<<BATCH * CH, 256, 0, stream>>>(x,   wkv_dw, tv, flag);

    lnorm_c<<<BATCH * PP, 256, 0, stream>>>(tk, ln_g, ln_b, flag);
    lnorm_c<<<BATCH * PP, 256, 0, stream>>>(tv, ln_g, ln_b, flag);

    {
        int ztot = 64 * 8 * (NKP - PP) + 64 * (NKP - PP) * HD;
        zpad_v<<<(ztot + 255) / 256, 256, 0, stream>>>(kpk, vpk);
    }

    dim3 gpw((PP + 63) / 64, CH / 64, BATCH);
    kv_gemm<<<gpw, 256, 0, stream>>>(wkv_pw, tk, kpk, flag, 1);
    kv_gemm<<<gpw, 256, 0, stream>>>(wkv_pw, tv, vpk, flag, 2);

    dim3 gg(HW / 128, CH / 128, BATCH);
    gemm_mfma<<<gg, 256, 0, stream>>>(wqb, semT, qt, flag, 1);

    dim3 ga(HW / 512, 64);
    attn_mfma<<<ga, 512, 0, stream>>>(qt, kpk, vpk, attT);

    gemm_mfma<<<gg, 256, 0, stream>>>(woutb, attT, d_out, flag, 0);
}

// Round 4
// 403.114 us; speedup vs baseline: 1.7588x; 1.3977x over previous
//
#include <hip/hip_runtime.h>
#include <hip/hip_bf16.h>

// S2Attention, dtype-adaptive, MFMA pipeline.
// B=8 C=512 H=W=64 HEADS=8 d=64 R=4 -> k/v spatial 17x17=289 (padded 320).
//
//  0) detect:  flag = externals f32 (1) vs bf16 (0)
//  0b) cvt_w:  wq, wout -> bf16 [512*512]; wprep: wg=bf16(w*g), ws=sum(w*g), wb=sum(w*b)
//  1) transpose_cvt: sem [z][512][4096] -> semT [z][4096][512] bf16 (vectorized)
//  2) dwconv:  spa,x -> tk,tv [B,C,289] f32 (plane-tiled, vectorized staging)
//  3) transpose_kv: tk,tv -> tT bf16 [16 zz][320 pos][512 c] (pads zeroed)
//     kv_stats: mean/rstd per (zz,pos) from tT (LN folded into kv_mfma epilogue)
//  4) kv_mfma: G = wg @ tT; epi applies rstd*(G - mean*ws) + wb, packs:
//       zz<8  -> kpack bf16 [bh][8 dg][320 nk][8 d]   (pads written 0)
//       zz>=8 -> vpack bf16 [bh][40 ng][64 d][8 nk]   (pads written 0)
//  5) gemm_mfma epi=1: q = wq @ sem -> qt bf16 [64][4096][64] in d_out (x0.125 folded)
//  6) attn_mfma: 512 thr, K/V staged in LDS once, 512 q-rows/block -> attT bf16
//  7) gemm_mfma epi=0: out = wout @ att -> d_out (flag dtype)

#define BATCH 8
#define CH 512
#define HW 4096
#define NHEADS 8
#define HD 64
#define PP 289
#define NKP 320

typedef __attribute__((ext_vector_type(8))) short bf16x8;
typedef __attribute__((ext_vector_type(4))) float f32x4;

__device__ inline float sanitize(float x) {
    unsigned u = __float_as_uint(x);
    if ((u & 0x7F800000u) == 0x7F800000u) return 0.0f;
    return x;
}
__device__ inline float ldin(const void* p, size_t i, int f32) {
    float x = f32 ? ((const float*)p)[i]
                  : __bfloat162float(((const __hip_bfloat16*)p)[i]);
    return sanitize(x);
}
__device__ inline void stout(void* p, size_t i, float v, int f32) {
    if (f32) ((float*)p)[i] = v;
    else     ((__hip_bfloat16*)p)[i] = __float2bfloat16(v);
}
__device__ inline short f2bf(float x) {   // RNE f32->bf16 (inputs pre-sanitized)
    unsigned u = __float_as_uint(x);
    unsigned r = (u + 0x7FFFu + ((u >> 16) & 1u)) >> 16;
    return (short)r;
}
__device__ inline float bf2f(short s) {
    unsigned u = ((unsigned)(unsigned short)s) << 16;
    return __uint_as_float(u);
}
__device__ inline void gload_lds16(const void* g, void* l) {
    __builtin_amdgcn_global_load_lds(
        (const __attribute__((address_space(1))) void*)g,
        (__attribute__((address_space(3))) void*)l, 16, 0, 0);
}

// ---------------- dtype detector ----------------
__global__ void detect_dtype(const unsigned short* __restrict__ w, int* __restrict__ flag) {
    __shared__ int red[256];
    int tid = threadIdx.x;
    int cnt = 0;
    for (int i = tid; i < 8192; i += 256) {
        unsigned e = w[i] & 0x7F80u;
        cnt += (e >= 0x4300u) ? 1 : 0;
    }
    red[tid] = cnt;
    __syncthreads();
    for (int o = 128; o; o >>= 1) { if (tid < o) red[tid] += red[tid + o]; __syncthreads(); }
    if (tid == 0) *flag = (red[0] > 500) ? 1 : 0;
}

// ---------------- weight convert: [512*512] ext dtype -> bf16 ----------------
__global__ __launch_bounds__(256)
void cvt_w(const void* __restrict__ in, short* __restrict__ out, const int* __restrict__ flag) {
    const int f32 = *flag;
    int i = (blockIdx.x * 256 + threadIdx.x) * 8;
#pragma unroll
    for (int e = 0; e < 8; ++e) out[i + e] = f2bf(ldin(in, i + e, f32));
}

// ---------------- wprep: wg = bf16(w*g), ws[m] = sum_c w*g, wb[m] = sum_c w*b ----
__global__ __launch_bounds__(256)
void wprep(const void* __restrict__ w, const void* __restrict__ g, const void* __restrict__ bb,
           short* __restrict__ wg, float* __restrict__ ws, float* __restrict__ wb,
           const int* __restrict__ flag) {
    const int f32 = *flag;
    const int tid = threadIdx.x;
    const int wave = tid >> 6, lane = tid & 63;
    const int m = blockIdx.x * 4 + wave;
    float s = 0.f, sb = 0.f;
    union { alignas(16) short sh[8]; int4 v; } u;
#pragma unroll
    for (int e = 0; e < 8; ++e) {
        int c = lane * 8 + e;
        float wv = ldin(w, (size_t)m * CH + c, f32);
        float gv = ldin(g, c, f32);
        float bv = ldin(bb, c, f32);
        float p = wv * gv;
        u.sh[e] = f2bf(p);
        s += p;
        sb += wv * bv;
    }
    *(int4*)(wg + (size_t)m * CH + lane * 8) = u.v;
#pragma unroll
    for (int o = 1; o < 64; o <<= 1) {
        s += __shfl_xor(s, o, 64);
        sb += __shfl_xor(sb, o, 64);
    }
    if (lane == 0) { ws[m] = s; wb[m] = sb; }
}

// ---------------- sem transpose+cvt: [z][512][4096] ext -> [z][4096][512] bf16 ----
__global__ __launch_bounds__(256)
void transpose_cvt(const void* __restrict__ in, short* __restrict__ outT,
                   const int* __restrict__ flag) {
    __shared__ short T[64 * 72];
    const int f32 = *flag;
    const int tid = threadIdx.x;
    const int z = blockIdx.z;
    const int c0 = blockIdx.y * 64, p0 = blockIdx.x * 64;
    {
        int c = tid >> 2, ps = (tid & 3) * 16;
        size_t src = ((size_t)z * CH + c0 + c) * HW + p0 + ps;
        short* dst = &T[c * 72 + ps];
        if (f32) {
            const float4* fp = (const float4*)((const float*)in + src);
#pragma unroll
            for (int v = 0; v < 4; ++v) {
                float4 w4 = fp[v];
                dst[v * 4 + 0] = f2bf(sanitize(w4.x));
                dst[v * 4 + 1] = f2bf(sanitize(w4.y));
                dst[v * 4 + 2] = f2bf(sanitize(w4.z));
                dst[v * 4 + 3] = f2bf(sanitize(w4.w));
            }
        } else {
            const int4* ip = (const int4*)((const short*)in + src);
#pragma unroll
            for (int v = 0; v < 2; ++v) {
                union { int4 q; short s[8]; } u; u.q = ip[v];
#pragma unroll
                for (int e = 0; e < 8; ++e) {
                    short sv = u.s[e];
                    if ((sv & 0x7F80) == 0x7F80) sv = 0;
                    dst[v * 8 + e] = sv;
                }
            }
        }
    }
    __syncthreads();
    {
        int p = tid >> 2, cs = (tid & 3) * 16;
        union { short s[16]; int4 v[2]; } u;
#pragma unroll
        for (int e = 0; e < 16; ++e) u.s[e] = T[(cs + e) * 72 + p];
        short* op = outT + ((size_t)z * HW + p0 + p) * CH + c0 + cs;
        *(int4*)op = u.v[0];
        *(int4*)(op + 8) = u.v[1];
    }
}

// ---------------- depthwise 4x4 stride4 pad2 conv, plane-tiled ----------------
__global__ __launch_bounds__(256)
void dwconv(const void* __restrict__ in, const void* __restrict__ w,
            float* __restrict__ out, const int* __restrict__ flag) {
    __shared__ float T[4096];
    __shared__ float wf[16];
    const int f32 = *flag;
    const int tid = threadIdx.x;
    const int bc = blockIdx.x;                 // b*CH + c
    const int c = bc & (CH - 1);
    size_t ibase = (size_t)bc * HW;
    if (tid < 16) wf[tid] = ldin(w, (size_t)c * 16 + tid, f32);
    if (f32) {
        const float4* ip = (const float4*)((const float*)in + ibase);
#pragma unroll
        for (int k = 0; k < 4; ++k) {
            float4 v = ip[k * 256 + tid];
            float* d = &T[(k * 256 + tid) * 4];
            d[0] = sanitize(v.x); d[1] = sanitize(v.y);
            d[2] = sanitize(v.z); d[3] = sanitize(v.w);
        }
    } else {
        const int4* ip = (const int4*)((const short*)in + ibase);
#pragma unroll
        for (int k = 0; k < 2; ++k) {
            union { int4 q; unsigned short s[8]; } u; u.q = ip[k * 256 + tid];
            float* d = &T[(k * 256 + tid) * 8];
#pragma unroll
            for (int e = 0; e < 8; ++e) {
                unsigned short sv = u.s[e];
                if ((sv & 0x7F80u) == 0x7F80u) sv = 0;
                d[e] = __bfloat162float(*(__hip_bfloat16*)&sv);
            }
        }
    }
    __syncthreads();
    for (int o = tid; o < PP; o += 256) {
        int oy = o / 17, ox = o % 17;
        float s = 0.f;
#pragma unroll
        for (int ky = 0; ky < 4; ++ky) {
            int iy = oy * 4 - 2 + ky;
            if ((unsigned)iy >= 64u) continue;
#pragma unroll
            for (int kx = 0; kx < 4; ++kx) {
                int ix = ox * 4 - 2 + kx;
                if ((unsigned)ix >= 64u) continue;
                s += T[iy * 64 + ix] * wf[ky * 4 + kx];
            }
        }
        out[(size_t)bc * PP + o] = s;
    }
}

// ---------------- t transpose: tk/tv f32 [b][512][289] -> tT bf16 [zz][320][512] ----
__global__ __launch_bounds__(256)
void transpose_kv(const float* __restrict__ tk, const float* __restrict__ tv,
                  short* __restrict__ tT) {
    __shared__ short T[64 * 72];
    const int tid = threadIdx.x;
    const int zz = blockIdx.z;                 // 0..7 = K batches, 8..15 = V batches
    const float* src = (zz < 8 ? tk : tv) + (size_t)(zz & 7) * CH * PP;
    const int c0 = blockIdx.y * 64, p0 = blockIdx.x * 64;
    {
        int c = tid >> 2, ps = (tid & 3) * 16;
        const float* sp = src + (size_t)(c0 + c) * PP + p0 + ps;
        short* dst = &T[c * 72 + ps];
#pragma unroll
        for (int e = 0; e < 16; ++e) {
            int pos = p0 + ps + e;
            dst[e] = (pos < PP) ? f2bf(sp[e]) : (short)0;
        }
    }
    __syncthreads();
    {
        int p = tid >> 2, cs = (tid & 3) * 16;
        union { short s[16]; int4 v[2]; } u;
#pragma unroll
        for (int e = 0; e < 16; ++e) u.s[e] = T[(cs + e) * 72 + p];
        short* op = tT + ((size_t)zz * NKP + p0 + p) * CH + c0 + cs;
        *(int4*)op = u.v[0];
        *(int4*)(op + 8) = u.v[1];
    }
}

// ---------------- per-(zz,pos) mean/rstd over C=512 (from bf16 tT) ----------------
__global__ __launch_bounds__(256)
void kv_stats(const short* __restrict__ tT, float* __restrict__ mean,
              float* __restrict__ rstd) {
    const int tid = threadIdx.x;
    const int wave = tid >> 6, lane = tid & 63;
    const int zz = blockIdx.y;
    const int pos = blockIdx.x * 4 + wave;
    bf16x8 v = *(const bf16x8*)(tT + ((size_t)zz * NKP + pos) * CH + lane * 8);
    float s = 0.f, sq = 0.f;
#pragma unroll
    for (int e = 0; e < 8; ++e) {
        float x = bf2f(v[e]);
        s += x; sq += x * x;
    }
#pragma unroll
    for (int o = 1; o < 64; o <<= 1) {
        s += __shfl_xor(s, o, 64);
        sq += __shfl_xor(sq, o, 64);
    }
    if (lane == 0) {
        float m = s * (1.0f / 512.0f);
        float var = sq * (1.0f / 512.0f) - m * m;
        mean[zz * NKP + pos] = m;
        rstd[zz * NKP + pos] = rsqrtf(fmaxf(var, 0.f) + 1e-5f);
    }
}

// ---------------- MFMA kv GEMM + folded LayerNorm + fragment-pack epilogue --------
// G[m][n] = sum_c wg[m][c] * tT[zz][n][c]; out = rstd[n]*(G - mean[n]*ws[m]) + wb[m]
// zz<8 -> kpack [bh][8][320][8]; zz>=8 -> vpack [bh][40][64][8]; pads written 0.
__global__ __launch_bounds__(256)
void kv_mfma(const short* __restrict__ wg, const short* __restrict__ tT,
             const float* __restrict__ mean, const float* __restrict__ rstd,
             const float* __restrict__ ws, const float* __restrict__ wb,
             short* __restrict__ kpack, short* __restrict__ vpack) {
    __shared__ short Alds[64 * 32];
    __shared__ short Blds[64 * 32];
    const int tid = threadIdx.x;
    const int wave = tid >> 6, lane = tid & 63;
    const int quad = lane >> 4, l15 = lane & 15;
    const int n0 = blockIdx.x * 64, m0 = blockIdx.y * 64;
    const int zz = blockIdx.z;
    const int row = tid >> 2, koff = (tid & 3) * 8;

    f32x4 acc[4];
#pragma unroll
    for (int nf = 0; nf < 4; ++nf) acc[nf] = (f32x4){0.f, 0.f, 0.f, 0.f};

    const short* abase = wg + (size_t)(m0 + row) * CH + koff;
    const short* bbase = tT + ((size_t)zz * NKP + n0 + row) * CH + koff;
    short* al = Alds + row * 32 + koff;
    short* bl = Blds + row * 32 + koff;

    for (int k0 = 0; k0 < CH; k0 += 32) {
        gload_lds16(abase + k0, al);
        gload_lds16(bbase + k0, bl);
        __syncthreads();
        bf16x8 af = *(const bf16x8*)(Alds + (wave * 16 + l15) * 32 + quad * 8);
#pragma unroll
        for (int nf = 0; nf < 4; ++nf) {
            bf16x8 bfr = *(const bf16x8*)(Blds + (nf * 16 + l15) * 32 + quad * 8);
            acc[nf] = __builtin_amdgcn_mfma_f32_16x16x32_bf16(af, bfr, acc[nf], 0, 0, 0);
        }
        __syncthreads();
    }
    // epilogue: LN affine + pack
    const int b = zz & 7;
    const bool isv = zz >= 8;
    float wsv[4], wbv[4];
#pragma unroll
    for (int i = 0; i < 4; ++i) {
        int m = m0 + wave * 16 + quad * 4 + i;
        wsv[i] = ws[m];
        wbv[i] = wb[m];
    }
#pragma unroll
    for (int nf = 0; nf < 4; ++nf) {
        int n = n0 + nf * 16 + l15;
        float mu = mean[zz * NKP + n];
        float rs = rstd[zz * NKP + n];
        bool vld = n < PP;
#pragma unroll
        for (int i = 0; i < 4; ++i) {
            int m = m0 + wave * 16 + quad * 4 + i;
            int head = m >> 6, d = m & 63;
            int bh = b * NHEADS + head;
            float val = vld ? (rs * (acc[nf][i] - mu * wsv[i]) + wbv[i]) : 0.f;
            short sv = f2bf(val);
            if (!isv) kpack[(((size_t)bh * 8 + (d >> 3)) * NKP + n) * 8 + (d & 7)] = sv;
            else      vpack[(((size_t)bh * 40 + (n >> 3)) * HD + d) * 8 + (n & 7)] = sv;
        }
    }
}

// ---------------- MFMA GEMM: C[z] = A[512][512]bf16 @ Bt[z][n][k]^T, N=4096 ----------------
// global_load_lds staging (linear [128][32] LDS, m97 structure).
// epi 0: plain store [z][m][n] flag dtype; epi 1: qt store bf16 [(z*8+h)][n][d] x0.125
__global__ __launch_bounds__(256)
void gemm_mfma(const short* __restrict__ A, const short* __restrict__ Bt,
               void* __restrict__ Cout, const int* __restrict__ flag, int epi) {
    __shared__ short Alds[128 * 32];
    __shared__ short Blds[128 * 32];
    const int f32 = *flag;
    const int tid = threadIdx.x;
    const int wave = tid >> 6, lane = tid & 63;
    const int quad = lane >> 4, l15 = lane & 15;
    const int wm = wave >> 1, wn = wave & 1;
    const int n0 = blockIdx.x * 128, m0 = blockIdx.y * 128;
    const int z = blockIdx.z;
    const int r4 = tid >> 2;          // 0..63: row within 64-row chunk
    const int s8 = (tid & 3) * 8;     // short offset within 32-short row

    f32x4 acc[4][4];
#pragma unroll
    for (int a = 0; a < 4; ++a)
#pragma unroll
        for (int b = 0; b < 4; ++b) acc[a][b] = (f32x4){0.f, 0.f, 0.f, 0.f};

    const short* abase = A + (size_t)(m0 + r4) * 512 + s8;
    const short* bbase = Bt + ((size_t)z * HW + n0 + r4) * 512 + s8;
    short* al = Alds + r4 * 32 + s8;
    short* bl = Blds + r4 * 32 + s8;

    for (int k0 = 0; k0 < 512; k0 += 32) {
#pragma unroll
        for (int c = 0; c < 2; ++c) {   // A: rows 0..127 in two 64-row chunks
            gload_lds16(abase + (size_t)(c * 64) * 512 + k0, al + c * 2048);
            gload_lds16(bbase + (size_t)(c * 64) * 512 + k0, bl + c * 2048);
        }
        __syncthreads();
        bf16x8 af[4], bfr[4];
#pragma unroll
        for (int a = 0; a < 4; ++a)
            af[a] = *(const bf16x8*)(Alds + (wm * 64 + a * 16 + l15) * 32 + quad * 8);
#pragma unroll
        for (int b = 0; b < 4; ++b)
            bfr[b] = *(const bf16x8*)(Blds + (wn * 64 + b * 16 + l15) * 32 + quad * 8);
#pragma unroll
        for (int a = 0; a < 4; ++a)
#pragma unroll
            for (int b = 0; b < 4; ++b)
                acc[a][b] = __builtin_amdgcn_mfma_f32_16x16x32_bf16(af[a], bfr[b], acc[a][b], 0, 0, 0);
        __syncthreads();
    }
#pragma unroll
    for (int a = 0; a < 4; ++a) {
        int mb = m0 + wm * 64 + a * 16 + quad * 4;
#pragma unroll
        for (int b = 0; b < 4; ++b) {
            int n = n0 + wn * 64 + b * 16 + l15;
            if (epi == 0) {
#pragma unroll
                for (int i = 0; i < 4; ++i)
                    stout(Cout, ((size_t)z * CH + mb + i) * HW + n, acc[a][b][i], f32);
            } else {
                union { alignas(8) short s[4]; int2 v; } u;
#pragma unroll
                for (int i = 0; i < 4; ++i) u.s[i] = f2bf(acc[a][b][i] * 0.125f);
                int h = mb >> 6, d = mb & 63;
                *(int2*)((short*)Cout + ((size_t)(z * NHEADS + h) * HW + n) * HD + d) = u.v;
            }
        }
    }
}

// ---------------- MFMA flash attention: K/V staged in LDS, 512 q-rows/block ----
// qt [64][4096][64] (pre-scaled x0.125)
// kpack [bh][8][320][8]: K frag-linear; vpack [bh][40][64][8]: V frag-linear (pads zeroed)
// out attT [8][4096][512] bf16 ([b][pos][c])
__global__ __launch_bounds__(512, 2)
void attn_mfma(const short* __restrict__ qt, const short* __restrict__ kpack,
               const short* __restrict__ vpack, short* __restrict__ attT) {
    __shared__ short Klds[8 * NKP * 8];   // 40960 B, linear copy of kpack head block
    __shared__ short Vlds[40 * HD * 8];   // 40960 B, linear copy of vpack head block
    __shared__ short PO[256 * 72];        // 36864 B: P tiles (loop) / O transpose (epi)
    const int tid = threadIdx.x;
    const int wave = tid >> 6, lane = tid & 63;
    const int quad = lane >> 4, l15 = lane & 15;
    const int bh = blockIdx.y;

    // stage K and V once per block (coalesced 16B direct-to-LDS)
    {
        const short* kbase = kpack + (size_t)bh * 8 * NKP * 8;
        const short* vbase = vpack + (size_t)bh * 40 * HD * 8;
#pragma unroll
        for (int rnd = 0; rnd < 5; ++rnd) {
            int off = (rnd * 512 + tid) * 8;
            gload_lds16(kbase + off, Klds + off);
            gload_lds16(vbase + off, Vlds + off);
        }
    }
    __syncthreads();

    short* pw = PO + (wave * 2) * 640;   // per-wave P tiles: [r][16q][40k]

    for (int it = 0; it < 2; ++it) {
        const int q0 = blockIdx.x * 512 + it * 256;
        // Q fragments: rows q0 + wave*32 + r*16 + l15, d-chunks quad*8 / 32+quad*8
        bf16x8 qf[2][2];
#pragma unroll
        for (int r = 0; r < 2; ++r) {
            const short* qp = qt + ((size_t)bh * HW + q0 + wave * 32 + r * 16 + l15) * HD + quad * 8;
            qf[r][0] = *(const bf16x8*)qp;
            qf[r][1] = *(const bf16x8*)(qp + 32);
        }
        f32x4 O[2][4];
        float lsum[2][4];
#pragma unroll
        for (int r = 0; r < 2; ++r)
#pragma unroll
            for (int df = 0; df < 4; ++df) {
                O[r][df] = (f32x4){0.f, 0.f, 0.f, 0.f};
                lsum[r][df] = 0.f;
            }

#pragma unroll
        for (int sc = 0; sc < 10; ++sc) {
            // K fragments from LDS (shared across r)
            bf16x8 kf0[2], kf1[2], vf[4];
#pragma unroll
            for (int c2 = 0; c2 < 2; ++c2) {
                const short* kp = Klds + ((size_t)quad * NKP + sc * 32 + c2 * 16 + l15) * 8;
                kf0[c2] = *(const bf16x8*)kp;
                kf1[c2] = *(const bf16x8*)(Klds + ((size_t)(4 + quad) * NKP + sc * 32 + c2 * 16 + l15) * 8);
            }
#pragma unroll
            for (int df = 0; df < 4; ++df)
                vf[df] = *(const bf16x8*)(Vlds + (((size_t)(sc * 4 + quad)) * HD + df * 16 + l15) * 8);
            // S = QK^T, exp, pack P (single-buffered per-wave tile; same-wave DS is in-order)
#pragma unroll
            for (int r = 0; r < 2; ++r) {
                short* pwr = pw + r * 640;
#pragma unroll
                for (int c2 = 0; c2 < 2; ++c2) {
                    f32x4 zz = (f32x4){0.f, 0.f, 0.f, 0.f};
                    zz = __builtin_amdgcn_mfma_f32_16x16x32_bf16(qf[r][0], kf0[c2], zz, 0, 0, 0);
                    f32x4 sfv = __builtin_amdgcn_mfma_f32_16x16x32_bf16(qf[r][1], kf1[c2], zz, 0, 0, 0);
                    int nk = sc * 32 + c2 * 16 + l15;
                    bool valid = nk < PP;
#pragma unroll
                    for (int i = 0; i < 4; ++i) {
                        float pv = valid ? __expf(fminf(sfv[i], 30.f)) : 0.f;
                        lsum[r][i] += pv;
                        pwr[(quad * 4 + i) * 40 + c2 * 16 + l15] = f2bf(pv);
                    }
                }
            }
            // RAW fence: P writes -> A-frag reads (wave-local)
            asm volatile("s_waitcnt lgkmcnt(0)" ::: "memory");
            __builtin_amdgcn_sched_barrier(0);
#pragma unroll
            for (int r = 0; r < 2; ++r) {
                bf16x8 pf = *(const bf16x8*)(pw + r * 640 + l15 * 40 + quad * 8);
#pragma unroll
                for (int df = 0; df < 4; ++df)
                    O[r][df] = __builtin_amdgcn_mfma_f32_16x16x32_bf16(pf, vf[df], O[r][df], 0, 0, 0);
            }
            asm volatile("" ::: "memory");  // keep next iter's P writes after these reads
        }
        // row sums
#pragma unroll
        for (int r = 0; r < 2; ++r)
#pragma unroll
            for (int i = 0; i < 4; ++i) {
                float s = lsum[r][i];
                s += __shfl_xor(s, 1, 64);
                s += __shfl_xor(s, 2, 64);
                s += __shfl_xor(s, 4, 64);
                s += __shfl_xor(s, 8, 64);
                lsum[r][i] = 1.0f / s;
            }
        __syncthreads();   // all waves done with P region before O overwrites PO
        // normalize + transpose O through PO, store [b][pos][c] coalesced
#pragma unroll
        for (int r = 0; r < 2; ++r)
#pragma unroll
            for (int df = 0; df < 4; ++df)
#pragma unroll
                for (int i = 0; i < 4; ++i)
                    PO[(wave * 32 + r * 16 + quad * 4 + i) * 72 + df * 16 + l15] =
                        f2bf(O[r][df][i] * lsum[r][i]);
        __syncthreads();
        {
            int q = tid >> 1, half = tid & 1;
            const short* src = PO + q * 72 + half * 32;
            int4 a0 = *(const int4*)(src);
            int4 a1 = *(const int4*)(src + 8);
            int4 a2 = *(const int4*)(src + 16);
            int4 a3 = *(const int4*)(src + 24);
            int b = bh >> 3, h = bh & 7;
            short* op = attT + ((size_t)b * HW + q0 + q) * CH + h * HD + half * 32;
            *(int4*)op = a0;
            *(int4*)(op + 8) = a1;
            *(int4*)(op + 16) = a2;
            *(int4*)(op + 24) = a3;
        }
        __syncthreads();   // PO O-region reads done before next subtile's P writes
    }
}

extern "C" void kernel_launch(void* const* d_in, const int* in_sizes, int n_in,
                              void* d_out, int out_size, void* d_ws, size_t ws_size,
                              hipStream_t stream) {
    const void* sem    = d_in[0];
    const void* spa    = d_in[1];
    const void* x      = d_in[2];
    const void* wq     = d_in[3];
    const void* wkv_dw = d_in[4];
    const void* ln_g   = d_in[5];
    const void* ln_b   = d_in[6];
    const void* wkv_pw = d_in[7];
    const void* wout   = d_in[8];

    const size_t nkv = (size_t)BATCH * CH * PP;      // 1,183,744
    char* p = (char*)d_ws;
    auto alloc = [&](size_t bytes) { char* r = p; p += (bytes + 255) & ~(size_t)255; return r; };
    int*   flag  = (int*)alloc(256);
    float* tk    = (float*)alloc(nkv * 4);
    float* tv    = (float*)alloc(nkv * 4);
    short* kpk   = (short*)alloc((size_t)64 * 8 * NKP * 8 * 2);    // 2.62 MB
    short* vpk   = (short*)alloc((size_t)64 * 40 * HD * 8 * 2);    // 2.62 MB
    short* semT  = (short*)alloc((size_t)BATCH * HW * CH * 2);
    short* attT  = (short*)alloc((size_t)BATCH * HW * CH * 2);
    short* wqb   = (short*)alloc((size_t)512 * 512 * 2);
    short* woutb = (short*)alloc((size_t)512 * 512 * 2);
    short* qt    = (short*)d_out;   // q staged bf16 in d_out; dead before final gemm

    // aliased scratch (lifetime-disjoint):
    short* tT    = (short*)d_out;               // [16][320][512] bf16 (5.24 MB), dead before qt
    short* wg    = attT;                        // [512][512] bf16, dead before attn writes attT
    float* ws    = (float*)(attT + (size_t)512 * 512);
    float* wb    = ws + 512;
    float* meanp = wb + 512;                    // [16][320]
    float* rstdp = meanp + 16 * NKP;            // [16][320]

    detect_dtype<<<1, 256, 0, stream>>>((const unsigned short*)sem, flag);

    cvt_w<<<128, 256, 0, stream>>>(wq, wqb, flag);
    cvt_w<<<128, 256, 0, stream>>>(wout, woutb, flag);
    wprep<<<128, 256, 0, stream>>>(wkv_pw, ln_g, ln_b, wg, ws, wb, flag);

    dim3 gt(HW / 64, CH / 64, BATCH);
    transpose_cvt<<<gt, 256, 0, stream>>>(sem, semT, flag);

    dwconv<<<BATCH * CH, 256, 0, stream>>>(spa, wkv_dw, tk, flag);
    dwconv<<<BATCH * CH, 256, 0, stream>>>(x,   wkv_dw, tv, flag);

    dim3 gtk(NKP / 64, CH / 64, 16);
    transpose_kv<<<gtk, 256, 0, stream>>>(tk, tv, tT);

    dim3 gs(NKP / 4, 16);
    kv_stats<<<gs, 256, 0, stream>>>(tT, meanp, rstdp);

    dim3 gkv(NKP / 64, CH / 64, 16);
    kv_mfma<<<gkv, 256, 0, stream>>>(wg, tT, meanp, rstdp, ws, wb, kpk, vpk);

    dim3 gg(HW / 128, CH / 128, BATCH);
    gemm_mfma<<<gg, 256, 0, stream>>>(wqb, semT, qt, flag, 1);

    dim3 ga(HW / 512, 64);
    attn_mfma<<<ga, 512, 0, stream>>>(qt, kpk, vpk, attT);

    gemm_mfma<<<gg, 256, 0, stream>>>(woutb, attT, d_out, flag, 0);
}

// Round 6
// 395.708 us; speedup vs baseline: 1.7918x; 1.0187x over previous
//
#include <hip/hip_runtime.h>
#include <hip/hip_bf16.h>

// S2Attention, dtype-adaptive, MFMA pipeline.
// B=8 C=512 H=W=64 HEADS=8 d=64 R=4 -> k/v spatial 17x17=289 (padded 320).
//
//  0) detect:  flag = externals f32 (1) vs bf16 (0)
//  0b) cvt_w:  wq, wout -> bf16 [512*512]; wprep: wg=bf16(w*g), ws=sum(w*g), wb=sum(w*b)
//  1) transpose_cvt: sem [z][512][4096] -> semT [z][4096][512] bf16 (b128 LDS, XOR swizzle)
//  2) dwconv:  spa,x -> tk,tv [B,C,289] f32 (plane-tiled, vectorized staging)
//  3) transpose_kv: tk,tv -> tT bf16 [16 zz][320 pos][512 c] (pads zeroed)
//     kv_stats: mean/rstd per (zz,pos) from tT (LN folded into kv_mfma epilogue)
//  4) kv_mfma: G = wg @ tT; epi applies rstd*(G - mean*ws) + wb, packs:
//       zz<8  -> kpack bf16 [bh][8 dg][320 nk][8 d]   (pads written 0)
//       zz>=8 -> vpack bf16 [bh][40 ng][64 d][8 nk]   (pads written 0)
//  5) gemm_mfma epi=1: q = wq @ sem -> qt bf16 [64][4096][64] in d_out
//     (x 0.125*log2e folded so attn uses exp2 directly)
//  6) attn_mfma: 1024 thr (16 waves, 4/SIMD), K/V in LDS, 1024 q-rows/block -> attT
//  7) gemm_mfma epi=0: out = wout @ att -> d_out (flag dtype)

#define BATCH 8
#define CH 512
#define HW 4096
#define NHEADS 8
#define HD 64
#define PP 289
#define NKP 320

typedef __attribute__((ext_vector_type(8))) short bf16x8;
typedef __attribute__((ext_vector_type(4))) float f32x4;

__device__ inline float sanitize(float x) {
    unsigned u = __float_as_uint(x);
    if ((u & 0x7F800000u) == 0x7F800000u) return 0.0f;
    return x;
}
__device__ inline float ldin(const void* p, size_t i, int f32) {
    float x = f32 ? ((const float*)p)[i]
                  : __bfloat162float(((const __hip_bfloat16*)p)[i]);
    return sanitize(x);
}
__device__ inline void stout(void* p, size_t i, float v, int f32) {
    if (f32) ((float*)p)[i] = v;
    else     ((__hip_bfloat16*)p)[i] = __float2bfloat16(v);
}
__device__ inline short f2bf(float x) {   // RNE f32->bf16 (inputs pre-sanitized)
    unsigned u = __float_as_uint(x);
    unsigned r = (u + 0x7FFFu + ((u >> 16) & 1u)) >> 16;
    return (short)r;
}
__device__ inline float bf2f(short s) {
    unsigned u = ((unsigned)(unsigned short)s) << 16;
    return __uint_as_float(u);
}
__device__ inline void gload_lds16(const void* g, void* l) {
    __builtin_amdgcn_global_load_lds(
        (const __attribute__((address_space(1))) void*)g,
        (__attribute__((address_space(3))) void*)l, 16, 0, 0);
}

// ---------------- dtype detector ----------------
__global__ void detect_dtype(const unsigned short* __restrict__ w, int* __restrict__ flag) {
    __shared__ int red[256];
    int tid = threadIdx.x;
    int cnt = 0;
    for (int i = tid; i < 8192; i += 256) {
        unsigned e = w[i] & 0x7F80u;
        cnt += (e >= 0x4300u) ? 1 : 0;
    }
    red[tid] = cnt;
    __syncthreads();
    for (int o = 128; o; o >>= 1) { if (tid < o) red[tid] += red[tid + o]; __syncthreads(); }
    if (tid == 0) *flag = (red[0] > 500) ? 1 : 0;
}

// ---------------- weight convert: [512*512] ext dtype -> bf16 ----------------
__global__ __launch_bounds__(256)
void cvt_w(const void* __restrict__ in, short* __restrict__ out, const int* __restrict__ flag) {
    const int f32 = *flag;
    int i = (blockIdx.x * 256 + threadIdx.x) * 8;
#pragma unroll
    for (int e = 0; e < 8; ++e) out[i + e] = f2bf(ldin(in, i + e, f32));
}

// ---------------- wprep: wg = bf16(w*g), ws[m] = sum_c w*g, wb[m] = sum_c w*b ----
__global__ __launch_bounds__(256)
void wprep(const void* __restrict__ w, const void* __restrict__ g, const void* __restrict__ bb,
           short* __restrict__ wg, float* __restrict__ ws, float* __restrict__ wb,
           const int* __restrict__ flag) {
    const int f32 = *flag;
    const int tid = threadIdx.x;
    const int wave = tid >> 6, lane = tid & 63;
    const int m = blockIdx.x * 4 + wave;
    float s = 0.f, sb = 0.f;
    union { alignas(16) short sh[8]; int4 v; } u;
#pragma unroll
    for (int e = 0; e < 8; ++e) {
        int c = lane * 8 + e;
        float wv = ldin(w, (size_t)m * CH + c, f32);
        float gv = ldin(g, c, f32);
        float bv = ldin(bb, c, f32);
        float p = wv * gv;
        u.sh[e] = f2bf(p);
        s += p;
        sb += wv * bv;
    }
    *(int4*)(wg + (size_t)m * CH + lane * 8) = u.v;
#pragma unroll
    for (int o = 1; o < 64; o <<= 1) {
        s += __shfl_xor(s, o, 64);
        sb += __shfl_xor(sb, o, 64);
    }
    if (lane == 0) { ws[m] = s; wb[m] = sb; }
}

// ---------------- sem transpose+cvt: [z][512][4096] ext -> [z][4096][512] bf16 ----
// 64x64 tile; LDS rows stride 72 shorts (144 B), 16B blocks XOR-swizzled by row bits 4-5
// so the column-read phase is conflict-free and writes are ds_write_b128.
__global__ __launch_bounds__(256)
void transpose_cvt(const void* __restrict__ in, short* __restrict__ outT,
                   const int* __restrict__ flag) {
    __shared__ short T[64 * 72];
    const int f32 = *flag;
    const int tid = threadIdx.x;
    const int z = blockIdx.z;
    const int c0 = blockIdx.y * 64, p0 = blockIdx.x * 64;
    {
        int c = tid >> 2, ps = (tid & 3) * 16;
        size_t src = ((size_t)z * CH + c0 + c) * HW + p0 + ps;
        union { alignas(16) short s[16]; int4 v[2]; } u;
        if (f32) {
            const float4* fp = (const float4*)((const float*)in + src);
#pragma unroll
            for (int v4 = 0; v4 < 4; ++v4) {
                float4 w4 = fp[v4];
                u.s[v4 * 4 + 0] = f2bf(sanitize(w4.x));
                u.s[v4 * 4 + 1] = f2bf(sanitize(w4.y));
                u.s[v4 * 4 + 2] = f2bf(sanitize(w4.z));
                u.s[v4 * 4 + 3] = f2bf(sanitize(w4.w));
            }
        } else {
            const int4* ip = (const int4*)((const short*)in + src);
#pragma unroll
            for (int v4 = 0; v4 < 2; ++v4) {
                union { int4 q; short s[8]; } t; t.q = ip[v4];
#pragma unroll
                for (int e = 0; e < 8; ++e) {
                    short sv = t.s[e];
                    if ((sv & 0x7F80) == 0x7F80) sv = 0;
                    u.s[v4 * 8 + e] = sv;
                }
            }
        }
        int base = c * 144 + ps * 2;              // byte offset, 16B-aligned
        int k = ((c >> 4) & 3) << 4;              // swizzle key from row bits 4-5
        *(int4*)((char*)T + (base ^ k)) = u.v[0];
        *(int4*)((char*)T + ((base + 16) ^ k)) = u.v[1];
    }
    __syncthreads();
    {
        int p = tid >> 2, cs = (tid & 3) * 16;
        union { short s[16]; int4 v[2]; } u;
#pragma unroll
        for (int e = 0; e < 16; ++e) {
            int row = cs + e;
            int byte = row * 144 + p * 2;
            u.s[e] = *(const short*)((const char*)T + (byte ^ (((row >> 4) & 3) << 4)));
        }
        short* op = outT + ((size_t)z * HW + p0 + p) * CH + c0 + cs;
        *(int4*)op = u.v[0];
        *(int4*)(op + 8) = u.v[1];
    }
}

// ---------------- depthwise 4x4 stride4 pad2 conv, plane-tiled ----------------
__global__ __launch_bounds__(256)
void dwconv(const void* __restrict__ in, const void* __restrict__ w,
            float* __restrict__ out, const int* __restrict__ flag) {
    __shared__ float T[4096];
    __shared__ float wf[16];
    const int f32 = *flag;
    const int tid = threadIdx.x;
    const int bc = blockIdx.x;                 // b*CH + c
    const int c = bc & (CH - 1);
    size_t ibase = (size_t)bc * HW;
    if (tid < 16) wf[tid] = ldin(w, (size_t)c * 16 + tid, f32);
    if (f32) {
        const float4* ip = (const float4*)((const float*)in + ibase);
#pragma unroll
        for (int k = 0; k < 4; ++k) {
            float4 v = ip[k * 256 + tid];
            float* d = &T[(k * 256 + tid) * 4];
            d[0] = sanitize(v.x); d[1] = sanitize(v.y);
            d[2] = sanitize(v.z); d[3] = sanitize(v.w);
        }
    } else {
        const int4* ip = (const int4*)((const short*)in + ibase);
#pragma unroll
        for (int k = 0; k < 2; ++k) {
            union { int4 q; unsigned short s[8]; } u; u.q = ip[k * 256 + tid];
            float* d = &T[(k * 256 + tid) * 8];
#pragma unroll
            for (int e = 0; e < 8; ++e) {
                unsigned short sv = u.s[e];
                if ((sv & 0x7F80u) == 0x7F80u) sv = 0;
                d[e] = __bfloat162float(*(__hip_bfloat16*)&sv);
            }
        }
    }
    __syncthreads();
    for (int o = tid; o < PP; o += 256) {
        int oy = o / 17, ox = o % 17;
        float s = 0.f;
#pragma unroll
        for (int ky = 0; ky < 4; ++ky) {
            int iy = oy * 4 - 2 + ky;
            if ((unsigned)iy >= 64u) continue;
#pragma unroll
            for (int kx = 0; kx < 4; ++kx) {
                int ix = ox * 4 - 2 + kx;
                if ((unsigned)ix >= 64u) continue;
                s += T[iy * 64 + ix] * wf[ky * 4 + kx];
            }
        }
        out[(size_t)bc * PP + o] = s;
    }
}

// ---------------- t transpose: tk/tv f32 [b][512][289] -> tT bf16 [zz][320][512] ----
__global__ __launch_bounds__(256)
void transpose_kv(const float* __restrict__ tk, const float* __restrict__ tv,
                  short* __restrict__ tT) {
    __shared__ short T[64 * 72];
    const int tid = threadIdx.x;
    const int zz = blockIdx.z;                 // 0..7 = K batches, 8..15 = V batches
    const float* src = (zz < 8 ? tk : tv) + (size_t)(zz & 7) * CH * PP;
    const int c0 = blockIdx.y * 64, p0 = blockIdx.x * 64;
    {
        int c = tid >> 2, ps = (tid & 3) * 16;
        const float* sp = src + (size_t)(c0 + c) * PP + p0 + ps;
        short* dst = &T[c * 72 + ps];
#pragma unroll
        for (int e = 0; e < 16; ++e) {
            int pos = p0 + ps + e;
            dst[e] = (pos < PP) ? f2bf(sp[e]) : (short)0;
        }
    }
    __syncthreads();
    {
        int p = tid >> 2, cs = (tid & 3) * 16;
        union { short s[16]; int4 v[2]; } u;
#pragma unroll
        for (int e = 0; e < 16; ++e) u.s[e] = T[(cs + e) * 72 + p];
        short* op = tT + ((size_t)zz * NKP + p0 + p) * CH + c0 + cs;
        *(int4*)op = u.v[0];
        *(int4*)(op + 8) = u.v[1];
    }
}

// ---------------- per-(zz,pos) mean/rstd over C=512 (from bf16 tT) ----------------
__global__ __launch_bounds__(256)
void kv_stats(const short* __restrict__ tT, float* __restrict__ mean,
              float* __restrict__ rstd) {
    const int tid = threadIdx.x;
    const int wave = tid >> 6, lane = tid & 63;
    const int zz = blockIdx.y;
    const int pos = blockIdx.x * 4 + wave;
    bf16x8 v = *(const bf16x8*)(tT + ((size_t)zz * NKP + pos) * CH + lane * 8);
    float s = 0.f, sq = 0.f;
#pragma unroll
    for (int e = 0; e < 8; ++e) {
        float x = bf2f(v[e]);
        s += x; sq += x * x;
    }
#pragma unroll
    for (int o = 1; o < 64; o <<= 1) {
        s += __shfl_xor(s, o, 64);
        sq += __shfl_xor(sq, o, 64);
    }
    if (lane == 0) {
        float m = s * (1.0f / 512.0f);
        float var = sq * (1.0f / 512.0f) - m * m;
        mean[zz * NKP + pos] = m;
        rstd[zz * NKP + pos] = rsqrtf(fmaxf(var, 0.f) + 1e-5f);
    }
}

// ---------------- MFMA kv GEMM + folded LayerNorm + fragment-pack epilogue --------
// G[m][n] = sum_c wg[m][c] * tT[zz][n][c]; out = rstd[n]*(G - mean[n]*ws[m]) + wb[m]
// zz<8 -> kpack [bh][8][320][8]; zz>=8 -> vpack [bh][40][64][8]; pads written 0.
__global__ __launch_bounds__(256)
void kv_mfma(const short* __restrict__ wg, const short* __restrict__ tT,
             const float* __restrict__ mean, const float* __restrict__ rstd,
             const float* __restrict__ ws, const float* __restrict__ wb,
             short* __restrict__ kpack, short* __restrict__ vpack) {
    __shared__ short Alds[64 * 32];
    __shared__ short Blds[64 * 32];
    const int tid = threadIdx.x;
    const int wave = tid >> 6, lane = tid & 63;
    const int quad = lane >> 4, l15 = lane & 15;
    const int n0 = blockIdx.x * 64, m0 = blockIdx.y * 64;
    const int zz = blockIdx.z;
    const int row = tid >> 2, koff = (tid & 3) * 8;

    f32x4 acc[4];
#pragma unroll
    for (int nf = 0; nf < 4; ++nf) acc[nf] = (f32x4){0.f, 0.f, 0.f, 0.f};

    const short* abase = wg + (size_t)(m0 + row) * CH + koff;
    const short* bbase = tT + ((size_t)zz * NKP + n0 + row) * CH + koff;
    short* al = Alds + row * 32 + koff;
    short* bl = Blds + row * 32 + koff;

    for (int k0 = 0; k0 < CH; k0 += 32) {
        gload_lds16(abase + k0, al);
        gload_lds16(bbase + k0, bl);
        __syncthreads();
        bf16x8 af = *(const bf16x8*)(Alds + (wave * 16 + l15) * 32 + quad * 8);
#pragma unroll
        for (int nf = 0; nf < 4; ++nf) {
            bf16x8 bfr = *(const bf16x8*)(Blds + (nf * 16 + l15) * 32 + quad * 8);
            acc[nf] = __builtin_amdgcn_mfma_f32_16x16x32_bf16(af, bfr, acc[nf], 0, 0, 0);
        }
        __syncthreads();
    }
    // epilogue: LN affine + pack
    const int b = zz & 7;
    const bool isv = zz >= 8;
    float wsv[4], wbv[4];
#pragma unroll
    for (int i = 0; i < 4; ++i) {
        int m = m0 + wave * 16 + quad * 4 + i;
        wsv[i] = ws[m];
        wbv[i] = wb[m];
    }
#pragma unroll
    for (int nf = 0; nf < 4; ++nf) {
        int n = n0 + nf * 16 + l15;
        float mu = mean[zz * NKP + n];
        float rs = rstd[zz * NKP + n];
        bool vld = n < PP;
#pragma unroll
        for (int i = 0; i < 4; ++i) {
            int m = m0 + wave * 16 + quad * 4 + i;
            int head = m >> 6, d = m & 63;
            int bh = b * NHEADS + head;
            float val = vld ? (rs * (acc[nf][i] - mu * wsv[i]) + wbv[i]) : 0.f;
            short sv = f2bf(val);
            if (!isv) kpack[(((size_t)bh * 8 + (d >> 3)) * NKP + n) * 8 + (d & 7)] = sv;
            else      vpack[(((size_t)bh * 40 + (n >> 3)) * HD + d) * 8 + (n & 7)] = sv;
        }
    }
}

// ---------------- MFMA GEMM: C[z] = A[512][512]bf16 @ Bt[z][n][k]^T, N=4096 ----------------
// global_load_lds staging (linear [128][32] LDS, m97 structure).
// epi 0: plain store [z][m][n] flag dtype; epi 1: qt store bf16 [(z*8+h)][n][d] x(0.125*log2e)
__global__ __launch_bounds__(256)
void gemm_mfma(const short* __restrict__ A, const short* __restrict__ Bt,
               void* __restrict__ Cout, const int* __restrict__ flag, int epi) {
    __shared__ short Alds[128 * 32];
    __shared__ short Blds[128 * 32];
    const int f32 = *flag;
    const int tid = threadIdx.x;
    const int wave = tid >> 6, lane = tid & 63;
    const int quad = lane >> 4, l15 = lane & 15;
    const int wm = wave >> 1, wn = wave & 1;
    const int n0 = blockIdx.x * 128, m0 = blockIdx.y * 128;
    const int z = blockIdx.z;
    const int r4 = tid >> 2;          // 0..63: row within 64-row chunk
    const int s8 = (tid & 3) * 8;     // short offset within 32-short row

    f32x4 acc[4][4];
#pragma unroll
    for (int a = 0; a < 4; ++a)
#pragma unroll
        for (int b = 0; b < 4; ++b) acc[a][b] = (f32x4){0.f, 0.f, 0.f, 0.f};

    const short* abase = A + (size_t)(m0 + r4) * 512 + s8;
    const short* bbase = Bt + ((size_t)z * HW + n0 + r4) * 512 + s8;
    short* al = Alds + r4 * 32 + s8;
    short* bl = Blds + r4 * 32 + s8;

    for (int k0 = 0; k0 < 512; k0 += 32) {
#pragma unroll
        for (int c = 0; c < 2; ++c) {   // A: rows 0..127 in two 64-row chunks
            gload_lds16(abase + (size_t)(c * 64) * 512 + k0, al + c * 2048);
            gload_lds16(bbase + (size_t)(c * 64) * 512 + k0, bl + c * 2048);
        }
        __syncthreads();
        bf16x8 af[4], bfr[4];
#pragma unroll
        for (int a = 0; a < 4; ++a)
            af[a] = *(const bf16x8*)(Alds + (wm * 64 + a * 16 + l15) * 32 + quad * 8);
#pragma unroll
        for (int b = 0; b < 4; ++b)
            bfr[b] = *(const bf16x8*)(Blds + (wn * 64 + b * 16 + l15) * 32 + quad * 8);
#pragma unroll
        for (int a = 0; a < 4; ++a)
#pragma unroll
            for (int b = 0; b < 4; ++b)
                acc[a][b] = __builtin_amdgcn_mfma_f32_16x16x32_bf16(af[a], bfr[b], acc[a][b], 0, 0, 0);
        __syncthreads();
    }
#pragma unroll
    for (int a = 0; a < 4; ++a) {
        int mb = m0 + wm * 64 + a * 16 + quad * 4;
#pragma unroll
        for (int b = 0; b < 4; ++b) {
            int n = n0 + wn * 64 + b * 16 + l15;
            if (epi == 0) {
#pragma unroll
                for (int i = 0; i < 4; ++i)
                    stout(Cout, ((size_t)z * CH + mb + i) * HW + n, acc[a][b][i], f32);
            } else {
                union { alignas(8) short s[4]; int2 v; } u;
#pragma unroll
                for (int i = 0; i < 4; ++i) u.s[i] = f2bf(acc[a][b][i] * 0.18033688011f);
                int h = mb >> 6, d = mb & 63;
                *(int2*)((short*)Cout + ((size_t)(z * NHEADS + h) * HW + n) * HD + d) = u.v;
            }
        }
    }
}

// ---------------- MFMA flash attention: 16 waves, K/V staged in LDS ----
// qt [64][4096][64] (pre-scaled x 0.125*log2e -> softmax uses exp2)
// kpack [bh][8][320][8]: K frag-linear; vpack [bh][40][64][8]: V frag-linear (pads zeroed)
// Pad k-rows are exact zeros -> each contributes exp2(0)=1 to the row sum; corrected by -31.
// out attT [8][4096][512] bf16 ([b][pos][c])
__global__ __launch_bounds__(1024, 1)
void attn_mfma(const short* __restrict__ qt, const short* __restrict__ kpack,
               const short* __restrict__ vpack, short* __restrict__ attT) {
    __shared__ short Klds[8 * NKP * 8];   // 40960 B
    __shared__ short Vlds[40 * HD * 8];   // 40960 B
    __shared__ short PO[20480];           // 40960 B: P tiles (sc loop) / O half-pass (epi)
    const int tid = threadIdx.x;
    const int wave = tid >> 6, lane = tid & 63;
    const int quad = lane >> 4, l15 = lane & 15;
    const int bh = blockIdx.y;
    const int b = bh >> 3, h = bh & 7;

    // stage K and V once per block (coalesced 16B direct-to-LDS)
    {
        const short* kbase = kpack + (size_t)bh * (8 * NKP * 8);
        const short* vbase = vpack + (size_t)bh * (40 * HD * 8);
        for (int i = tid; i < 2560; i += 1024) {   // last trip: waves 0-7 only (wave-uniform)
            gload_lds16(kbase + i * 8, Klds + i * 8);
            gload_lds16(vbase + i * 8, Vlds + i * 8);
        }
    }
    __syncthreads();

    short* pw = PO + wave * 1280;   // per-wave P tiles: [r][16q][40k]

    for (int it = 0; it < 2; ++it) {
        const int q0 = blockIdx.x * 1024 + it * 512;
        // Q fragments: rows q0 + wave*32 + r*16 + l15, d-chunks quad*8 / 32+quad*8
        bf16x8 qf[2][2];
#pragma unroll
        for (int r = 0; r < 2; ++r) {
            const short* qp = qt + ((size_t)bh * HW + q0 + wave * 32 + r * 16 + l15) * HD + quad * 8;
            qf[r][0] = *(const bf16x8*)qp;
            qf[r][1] = *(const bf16x8*)(qp + 32);
        }
        f32x4 O[2][4];
        float lsum[2][4];
#pragma unroll
        for (int r = 0; r < 2; ++r)
#pragma unroll
            for (int df = 0; df < 4; ++df) {
                O[r][df] = (f32x4){0.f, 0.f, 0.f, 0.f};
                lsum[r][df] = 0.f;
            }

#pragma unroll
        for (int sc = 0; sc < 10; ++sc) {
            // K/V fragments from LDS (shared across r)
            bf16x8 kf0[2], kf1[2], vf[4];
#pragma unroll
            for (int c2 = 0; c2 < 2; ++c2) {
                const short* kp = Klds + ((size_t)quad * NKP + sc * 32 + c2 * 16 + l15) * 8;
                kf0[c2] = *(const bf16x8*)kp;
                kf1[c2] = *(const bf16x8*)(Klds + ((size_t)(4 + quad) * NKP + sc * 32 + c2 * 16 + l15) * 8);
            }
#pragma unroll
            for (int df = 0; df < 4; ++df)
                vf[df] = *(const bf16x8*)(Vlds + (((size_t)(sc * 4 + quad)) * HD + df * 16 + l15) * 8);
            // S = QK^T (x log2e folded), exp2, pack P (per-wave tile; same-wave DS in-order)
#pragma unroll
            for (int r = 0; r < 2; ++r) {
                short* pwr = pw + r * 640;
#pragma unroll
                for (int c2 = 0; c2 < 2; ++c2) {
                    f32x4 zz = (f32x4){0.f, 0.f, 0.f, 0.f};
                    zz = __builtin_amdgcn_mfma_f32_16x16x32_bf16(qf[r][0], kf0[c2], zz, 0, 0, 0);
                    f32x4 sfv = __builtin_amdgcn_mfma_f32_16x16x32_bf16(qf[r][1], kf1[c2], zz, 0, 0, 0);
#pragma unroll
                    for (int i = 0; i < 4; ++i) {
                        float pv = __builtin_amdgcn_exp2f(fminf(sfv[i], 43.f));
                        lsum[r][i] += pv;
                        pwr[(quad * 4 + i) * 40 + c2 * 16 + l15] = f2bf(pv);
                    }
                }
            }
            // RAW fence: P writes -> A-frag reads (wave-local)
            asm volatile("s_waitcnt lgkmcnt(0)" ::: "memory");
            __builtin_amdgcn_sched_barrier(0);
            __builtin_amdgcn_s_setprio(1);
#pragma unroll
            for (int r = 0; r < 2; ++r) {
                bf16x8 pf = *(const bf16x8*)(pw + r * 640 + l15 * 40 + quad * 8);
#pragma unroll
                for (int df = 0; df < 4; ++df)
                    O[r][df] = __builtin_amdgcn_mfma_f32_16x16x32_bf16(pf, vf[df], O[r][df], 0, 0, 0);
            }
            __builtin_amdgcn_s_setprio(0);
            asm volatile("" ::: "memory");  // keep next iter's P writes after these reads
        }
        // row sums: butterfly over the 16 lanes holding each row group; -31 pad correction
#pragma unroll
        for (int r = 0; r < 2; ++r)
#pragma unroll
            for (int i = 0; i < 4; ++i) {
                float s = lsum[r][i];
                s += __shfl_xor(s, 1, 64);
                s += __shfl_xor(s, 2, 64);
                s += __shfl_xor(s, 4, 64);
                s += __shfl_xor(s, 8, 64);
                lsum[r][i] = 1.0f / (s - 31.0f);
            }
        __syncthreads();   // all waves done with P region before O overwrites PO
        // normalize + transpose O through PO in two 256-row half-passes
#pragma unroll
        for (int hp = 0; hp < 2; ++hp) {
            if ((wave >> 3) == hp) {
                int wl = wave & 7;
#pragma unroll
                for (int r = 0; r < 2; ++r)
#pragma unroll
                    for (int df = 0; df < 4; ++df)
#pragma unroll
                        for (int i = 0; i < 4; ++i)
                            PO[(wl * 32 + r * 16 + quad * 4 + i) * 72 + df * 16 + l15] =
                                f2bf(O[r][df][i] * lsum[r][i]);
            }
            __syncthreads();
            {
                int q = tid >> 2, seg = tid & 3;
                const short* src = PO + q * 72 + seg * 16;
                int4 a0 = *(const int4*)(src);
                int4 a1 = *(const int4*)(src + 8);
                short* op = attT + ((size_t)b * HW + q0 + hp * 256 + q) * CH + h * HD + seg * 16;
                *(int4*)op = a0;
                *(int4*)(op + 8) = a1;
            }
            __syncthreads();
        }
    }
}

extern "C" void kernel_launch(void* const* d_in, const int* in_sizes, int n_in,
                              void* d_out, int out_size, void* d_ws, size_t ws_size,
                              hipStream_t stream) {
    const void* sem    = d_in[0];
    const void* spa    = d_in[1];
    const void* x      = d_in[2];
    const void* wq     = d_in[3];
    const void* wkv_dw = d_in[4];
    const void* ln_g   = d_in[5];
    const void* ln_b   = d_in[6];
    const void* wkv_pw = d_in[7];
    const void* wout   = d_in[8];

    const size_t nkv = (size_t)BATCH * CH * PP;      // 1,183,744
    char* p = (char*)d_ws;
    auto alloc = [&](size_t bytes) { char* r = p; p += (bytes + 255) & ~(size_t)255; return r; };
    int*   flag  = (int*)alloc(256);
    float* tk    = (float*)alloc(nkv * 4);
    float* tv    = (float*)alloc(nkv * 4);
    short* kpk   = (short*)alloc((size_t)64 * 8 * NKP * 8 * 2);    // 2.62 MB
    short* vpk   = (short*)alloc((size_t)64 * 40 * HD * 8 * 2);    // 2.62 MB
    short* semT  = (short*)alloc((size_t)BATCH * HW * CH * 2);
    short* attT  = (short*)alloc((size_t)BATCH * HW * CH * 2);
    short* wqb   = (short*)alloc((size_t)512 * 512 * 2);
    short* woutb = (short*)alloc((size_t)512 * 512 * 2);
    short* qt    = (short*)d_out;   // q staged bf16 in d_out; dead before final gemm

    // aliased scratch (lifetime-disjoint):
    short* tT    = (short*)d_out;               // [16][320][512] bf16 (5.24 MB), dead before qt
    short* wg    = attT;                        // [512][512] bf16, dead before attn writes attT
    float* ws    = (float*)(attT + (size_t)512 * 512);
    float* wb    = ws + 512;
    float* meanp = wb + 512;                    // [16][320]
    float* rstdp = meanp + 16 * NKP;            // [16][320]

    detect_dtype<<<1, 256, 0, stream>>>((const unsigned short*)sem, flag);

    cvt_w<<<128, 256, 0, stream>>>(wq, wqb, flag);
    cvt_w<<<128, 256, 0, stream>>>(wout, woutb, flag);
    wprep<<<128, 256, 0, stream>>>(wkv_pw, ln_g, ln_b, wg, ws, wb, flag);

    dim3 gt(HW / 64, CH / 64, BATCH);
    transpose_cvt<<<gt, 256, 0, stream>>>(sem, semT, flag);

    dwconv<<<BATCH * CH, 256, 0, stream>>>(spa, wkv_dw, tk, flag);
    dwconv<<<BATCH * CH, 256, 0, stream>>>(x,   wkv_dw, tv, flag);

    dim3 gtk(NKP / 64, CH / 64, 16);
    transpose_kv<<<gtk, 256, 0, stream>>>(tk, tv, tT);

    dim3 gs(NKP / 4, 16);
    kv_stats<<<gs, 256, 0, stream>>>(tT, meanp, rstdp);

    dim3 gkv(NKP / 64, CH / 64, 16);
    kv_mfma<<<gkv, 256, 0, stream>>>(wg, tT, meanp, rstdp, ws, wb, kpk, vpk);

    dim3 gg(HW / 128, CH / 128, BATCH);
    gemm_mfma<<<gg, 256, 0, stream>>>(wqb, semT, qt, flag, 1);

    dim3 ga(HW / 1024, 64);
    attn_mfma<<<ga, 1024, 0, stream>>>(qt, kpk, vpk, attT);

    gemm_mfma<<<gg, 256, 0, stream>>>(woutb, attT, d_out, flag, 0);
}